// Round 8
// baseline (388.190 us; speedup 1.0000x reference)
//
#include <hip/hip_runtime.h>

#define BB 4
#define TT 1024
#define CCH 2048
#define HH 16
#define HDIM 128
#define NBLK 1024
#define MM (BB*TT)          // 4096
#define N1 (3*CCH)          // 6144
#define NQT 16              // T / 64

typedef _Float16 f16;
typedef _Float16 half8 __attribute__((ext_vector_type(8)));
typedef _Float16 half4 __attribute__((ext_vector_type(4)));
typedef float floatx4 __attribute__((ext_vector_type(4)));

// async global->LDS, 16B per lane. LDS dest = wave-uniform base + lane*16.
__device__ __forceinline__ void g2lds16(const void* g, void* l) {
    __builtin_amdgcn_global_load_lds((const __attribute__((address_space(1))) void*)g,
                                     (__attribute__((address_space(3))) void*)l, 16, 0, 0);
}

// ---- fused prep: z=0 transpose Wa -> WaT f16, z=1 Wp -> WpT, z=2 cvt x -> f16 ----
__global__ void k_prep(const float* __restrict__ Wa, const float* __restrict__ Wp,
                       const float* __restrict__ x,
                       f16* __restrict__ WaT, f16* __restrict__ WpT,
                       f16* __restrict__ x16) {
    int z = blockIdx.z;
    if (z == 2) {   // convert: MM*CCH/4 float4s
        int i = (blockIdx.y * 192 + blockIdx.x) * 256 + threadIdx.x + threadIdx.y * 32;
        if (i >= MM * CCH / 4) return;
        float4 v = ((const float4*)x)[i];
        union { ushort4 u; f16 h[4]; } o;
        o.h[0] = (f16)v.x; o.h[1] = (f16)v.y; o.h[2] = (f16)v.z; o.h[3] = (f16)v.w;
        ((ushort4*)x16)[i] = o.u;
        return;
    }
    const float* in = (z == 0) ? Wa : Wp;
    f16* out = (z == 0) ? WaT : WpT;
    int Cc = (z == 0) ? N1 : CCH;
    if (blockIdx.x * 32 >= Cc) return;
    __shared__ float tile[32][33];
    int c0 = blockIdx.x * 32, r0 = blockIdx.y * 32;
    int tx = threadIdx.x, ty = threadIdx.y;
#pragma unroll
    for (int k = 0; k < 4; k++) {
        int r = ty + k * 8;
        tile[r][tx] = in[(size_t)(r0 + r) * Cc + c0 + tx];
    }
    __syncthreads();
#pragma unroll
    for (int k = 0; k < 4; k++) {
        int r = ty + k * 8;
        out[(size_t)(c0 + r) * CCH + r0 + tx] = (f16)tile[tx][r];
    }
}

// ------- transpose f16 per-head [T][HD] -> [HD][T] (for V) -------
__global__ void k_trv(const f16* __restrict__ in, f16* __restrict__ out) {
    __shared__ f16 tile[32][34];
    int bh = blockIdx.z;
    int h0 = blockIdx.x * 32, t0 = blockIdx.y * 32;
    int tx = threadIdx.x, ty = threadIdx.y;
#pragma unroll
    for (int k = 0; k < 4; k++) {
        int t = ty + k * 8;
        tile[t][tx] = in[((size_t)bh * TT + t0 + t) * HDIM + h0 + tx];
    }
    __syncthreads();
#pragma unroll
    for (int k = 0; k < 4; k++) {
        int r = ty + k * 8;
        out[((size_t)bh * HDIM + h0 + r) * TT + t0 + tx] = tile[tx][r];
    }
}

// ---------------- global histogram over all B*T tokens ----------------
__global__ void k_hist(const int* __restrict__ tok, int* __restrict__ cnt) {
    int i = blockIdx.x * blockDim.x + threadIdx.x;
    if (i < MM) atomicAdd(cnt + tok[i], 1);
}

// ------- per-batch inclusive scan of 1/count; also padding bias -------
__global__ __launch_bounds__(1024) void k_scan(const int* __restrict__ tok,
                                               const int* __restrict__ cnt,
                                               const int* __restrict__ pm,
                                               float* __restrict__ tpos,
                                               float* __restrict__ pb) {
    __shared__ float s[TT];
    int b = blockIdx.x, t = threadIdx.x;
    s[t] = 1.0f / ((float)cnt[tok[b * TT + t]] + 1e-10f);
    __syncthreads();
    for (int off = 1; off < TT; off <<= 1) {
        float add = (t >= off) ? s[t - off] : 0.0f;
        __syncthreads();
        s[t] += add;
        __syncthreads();
    }
    tpos[b * TT + t] = s[t];
    pb[b * TT + t] = pm[b * TT + t] ? 0.0f : -1e30f;
}

// ------- rope table: tab[row*64+j] = (cos, sin) of tpos[row]*10000^(-j/64) -------
__global__ void k_rope(const float* __restrict__ tpos, float2* __restrict__ tab) {
    int i = blockIdx.x * 256 + threadIdx.x;     // MM*64 entries
    int row = i >> 6, j = i & 63;
    float f = tpos[row] * expf((float)j * -0.14391156929f);   // ln(10000)/64
    float sn, cn; sincosf(f, &sn, &cn);
    tab[i] = make_float2(cn, sn);
}

// ===== 256x128 GEMM, 8 waves x (64x64), BK=64, triple-buffered counted-vmcnt =====
// ROUND-8 (port-ratio fix): schedule/LDS/swizzle/grids IDENTICAL to round 7
//   (best passing: 130us, MfmaUtil 34%, conflicts 0). ONE change: wave grid
//   2x4 (128x32/wave) -> 4x2 (64x64/wave). LDS-port traffic per CU per K-tile
//   = Sum_w (Mw+Nw)*BK*2B: 8*(160)*128B = 160KB (1920cy) -> 8*(128)*128B =
//   128KB (1536cy) vs 1240cy MFMA: ceiling 65% -> 81%, phases balanced
//   (8 reads per phase per wave: 4 A + 4 B).
// B cols per wave: (nf&1)*64 + wn*32 + (nf>>1)*16 + l16 -> rope pairs (d,d+64)
//   = (nf even, nf odd) stay in-wave. All read rows still have row&7 == l16&7,
//   so the rotation-swizzle read chunks ck0/ck1 are unchanged (conflicts 0).
// Pipeline per K-tile t (2 phases, 1 barrier each, buffers rotate cur<-nxt<-stg):
//   ph1: RD S1<-cur.kk1; STAGE t+2->stg; MFMA S0 (t.kk0); vmcnt(6); BAR
//   ph2: RD S0<-nxt.kk0; MFMA S1 (t.kk1); BAR
#define BAR() __builtin_amdgcn_s_barrier()
#define RDA(S, base, ck) do { _Pragma("unroll") for (int m_ = 0; m_ < 4; m_++) \
    S[m_] = *(const half8*)((base) + aoffb + (m_ << 11) + (ck)); } while (0)
#define RDB(S, base, ck) do { _Pragma("unroll") for (int n_ = 0; n_ < 4; n_++) \
    S[n_] = *(const half8*)((base) + bofs[n_] + (ck)); } while (0)
#define STAGEA(t, base) do { _Pragma("unroll") for (int k_ = 0; k_ < 4; k_++) \
    g2lds16(Ab + (size_t)(k_ * 64) * 2048 + ((t) << 6) + srcr, \
            (base) + (w * 8 + k_ * 64) * 128); } while (0)
#define STAGEB(t, base) do { _Pragma("unroll") for (int k_ = 0; k_ < 2; k_++) \
    g2lds16(Bb + (size_t)(k_ * 64) * 2048 + ((t) << 6) + srcr, \
            (base) + (w * 8 + k_ * 64) * 128); } while (0)
#define MF16(SA, SB) do { _Pragma("unroll") for (int m_ = 0; m_ < 4; m_++) \
    _Pragma("unroll") for (int n_ = 0; n_ < 4; n_++) \
    acc[m_][n_] = __builtin_amdgcn_mfma_f32_16x16x32_f16(SA[m_], SB[n_], acc[m_][n_], 0, 0, 0); } while (0)

template <int MODE>   // 1: QKV fused rope epilogue (N=6144); 0: plain f32 C (N=2048)
__global__ __launch_bounds__(512, 2) void k_gemm8(const f16* __restrict__ A,
                                                  const f16* __restrict__ Bt,
                                                  float* __restrict__ Cp,
                                                  const float2* __restrict__ tab,
                                                  const float* __restrict__ cs,
                                                  f16* __restrict__ qr,
                                                  f16* __restrict__ kr,
                                                  f16* __restrict__ vsc) {
    const float SCALE = 0.08838834764831845f;   // 1/sqrt(128), folded into q
    const int NBN = MODE ? 48 : 16;
    const int NWG = MODE ? 768 : 256;
    const int CPX = NWG >> 3;
    __shared__ __align__(16) f16 As[3 * 16384];   // [3 buf][256][64], 96KB
    __shared__ __align__(16) f16 Bs[3 * 8192];    // [3 buf][128][64], 48KB

    int bid = blockIdx.x;
    int s = (bid & 7) * CPX + (bid >> 3);          // XCD swizzle (bijective: NWG%8==0)
    int bm = s / NBN, bn = s % NBN;

    int tid = threadIdx.x;
    int w = tid >> 6, lane = tid & 63, quad = lane >> 4, l16 = lane & 15;
    int wm = w & 3, wn = w >> 2;                   // 4 x 2 wave grid, 64x64 each

    const f16* Ab = A + (size_t)(bm << 8) * 2048;
    const f16* Bb = Bt + (size_t)(bn << 7) * 2048;

    // rotation-swizzle staging source: lane = (row rl, chunk cl); source chunk
    // (cl - row)&7 (row-block offsets are ==0 mod 8, so gl is row-invariant).
    int rl = lane >> 3, cl = lane & 7;
    int gl = (cl - rl) & 7;
    int srcr = (w * 8 + rl) * 2048 + gl * 8;

    // frag-read bases; read chunk (g + row)&7, row&7 == l16&7, g = kk*4 + quad.
    const int aoffb = (wm * 64 + l16) << 7;
    const int bofs[4] = { (wn * 32 + l16) << 7,        (wn * 32 + 64 + l16) << 7,
                          (wn * 32 + 16 + l16) << 7,   (wn * 32 + 80 + l16) << 7 };
    const int ck0 = ((quad + l16) & 7) << 4;
    const int ck1 = ck0 ^ 64;

    floatx4 acc[4][4];
#pragma unroll
    for (int i = 0; i < 4; i++)
#pragma unroll
        for (int j = 0; j < 4; j++) acc[i][j] = (floatx4){0.f, 0.f, 0.f, 0.f};

    half8 S0a[4], S1a[4];
    half8 S0b[4], S1b[4];

    char* a0 = (char*)As; char* a1 = a0 + 32768; char* a2 = a0 + 65536;
    char* b0 = (char*)Bs; char* b1 = b0 + 16384; char* b2 = b0 + 32768;

    // prologue: stage t0 -> buf0 (6 loads/wave), t1 -> buf1 (6)
    STAGEA(0, a0); STAGEB(0, b0);
    STAGEA(1, a1); STAGEB(1, b1);
    asm volatile("s_waitcnt vmcnt(6)" ::: "memory");   // t0 landed (t1 in flight)
    BAR();
    RDA(S0a, a0, ck0); RDB(S0b, b0, ck0);              // t0.kk0 -> S0

#pragma unroll 1
    for (int t = 0; t < 32; ++t) {
        // ph1: RD S1 <- cur.kk1; stage t+2 -> stg; MFMA t.kk0; counted vmcnt; BAR
        RDA(S1a, a0, ck1); RDB(S1b, b0, ck1);
        if (t + 2 < 32) { STAGEA(t + 2, a2); STAGEB(t + 2, b2); }
        __builtin_amdgcn_s_setprio(1); MF16(S0a, S0b); __builtin_amdgcn_s_setprio(0);
        if (t < 30) { asm volatile("s_waitcnt vmcnt(6)" ::: "memory"); }
        else        { asm volatile("s_waitcnt vmcnt(0)" ::: "memory"); }
        BAR();
        // ph2: RD S0 <- nxt.kk0; MFMA t.kk1; BAR
        if (t < 31) { RDA(S0a, a1, ck0); RDB(S0b, b1, ck0); }
        __builtin_amdgcn_s_setprio(1); MF16(S1a, S1b); __builtin_amdgcn_s_setprio(0);
        BAR();
        // rotate buffers: cur <- nxt <- stg <- cur
        char* ta = a0; a0 = a1; a1 = a2; a2 = ta;
        char* tb = b0; b0 = b1; b1 = b2; b2 = tb;
    }

    // ---- epilogue: rows = bm*256 + wm*64 + mf*16 + quad*4 + r
    //      cols = bn*128 + (nf&1)*64 + wn*32 + (nf>>1)*16 + l16
    if (MODE == 0) {
#pragma unroll
        for (int mf = 0; mf < 4; mf++)
#pragma unroll
            for (int nf = 0; nf < 4; nf++) {
                int col = (bn << 7) + ((nf & 1) << 6) + wn * 32 + ((nf >> 1) << 4) + l16;
#pragma unroll
                for (int r = 0; r < 4; r++) {
                    int row = (bm << 8) + wm * 64 + mf * 16 + (quad << 2) + r;
                    Cp[(size_t)row * CCH + col] = acc[mf][nf][r];
                }
            }
    } else {
        int type = bn >> 4;              // 0=q, 1=k, 2=v (16 blocks per 2048-col chunk)
        int h = bn & 15;                 // one head per block
        if (type < 2) {
            f16* outp = (type == 0) ? qr : kr;
#pragma unroll
            for (int mf = 0; mf < 4; mf++)
#pragma unroll
                for (int r = 0; r < 4; r++) {
                    int row = (bm << 8) + wm * 64 + mf * 16 + (quad << 2) + r;
#pragma unroll
                    for (int p = 0; p < 2; p++) {     // rope pairs: nf {0,1}, {2,3}
                        int d1 = wn * 32 + p * 16 + l16;   // 0..63
                        float2 tc = tab[row * 64 + d1];
                        float a1v = acc[mf][2 * p][r], a2v = acc[mf][2 * p + 1][r];
                        float o1 = a1v * tc.x - a2v * tc.y;
                        float o2 = a2v * tc.x + a1v * tc.y;
                        if (type == 0) {
                            if (d1 == 63) o2 = 1.0f;          // q[...,-1]=1 (before scale)
                            o1 *= SCALE; o2 *= SCALE;
                        } else {
                            if (d1 == 63) o2 = cs[row];       // k[...,-1]=cum_scores
                        }
                        size_t ob = ((size_t)((row >> 10) * HH + h) * TT + (row & 1023)) * HDIM + d1;
                        outp[ob] = (f16)o1;
                        outp[ob + 64] = (f16)o2;
                    }
                }
        } else {
#pragma unroll
            for (int mf = 0; mf < 4; mf++)
#pragma unroll
                for (int r = 0; r < 4; r++) {
                    int row = (bm << 8) + wm * 64 + mf * 16 + (quad << 2) + r;
                    float ve = __expf(cs[row]);
#pragma unroll
                    for (int nf = 0; nf < 4; nf++) {
                        int d = ((nf & 1) << 6) + wn * 32 + ((nf >> 1) << 4) + l16;
                        size_t ob = ((size_t)((row >> 10) * HH + h) * TT + (row & 1023)) * HDIM + d;
                        vsc[ob] = (f16)(acc[mf][nf][r] * ve);
                    }
                }
        }
    }
}

// ---------------- causal flash attention, S^T formulation ----------------
__global__ __launch_bounds__(256) void k_attn(const f16* __restrict__ qr,
                                              const f16* __restrict__ kr,
                                              const f16* __restrict__ vt,
                                              const float* __restrict__ pb,
                                              f16* __restrict__ y) {
    __shared__ __align__(16) f16 Ks[64 * 136];   // [kv][hd], pad 128->136
    __shared__ __align__(16) f16 Vs[128 * 72];   // [hd][kv], pad 64->72
    __shared__ float pbs[64];
    int p = blockIdx.x & (NQT / 2 - 1);
    int bh = blockIdx.x >> 3;
    int b = bh >> 4, h = bh & 15;
    int tid = threadIdx.x;
    int w = tid >> 6, lane = tid & 63, quad = lane >> 4, l16 = lane & 15;
#pragma unroll
    for (int pass = 0; pass < 2; pass++) {
        int qt = pass ? (NQT - 1 - p) : p;
        int q0 = qt << 6;
        int qg = q0 + w * 16 + l16;                  // this lane's q column
        const f16* Qp = qr + ((size_t)bh * TT + qg) * HDIM;
        half8 qf[4];                                  // B-op: Q[q=l16][hd=kc*32+quad*8+e]
#pragma unroll
        for (int kc = 0; kc < 4; kc++) qf[kc] = *(const half8*)&Qp[kc * 32 + (quad << 3)];
        floatx4 O[8];                                 // O^T[hd][q] C-frags
#pragma unroll
        for (int i = 0; i < 8; i++) O[i] = (floatx4){0.f, 0.f, 0.f, 0.f};
        float mx = -1e30f, ls = 0.f;
        for (int kt = 0; kt <= qt; kt++) {
            __syncthreads();
            const f16* Kb = kr + ((size_t)bh * TT + (kt << 6)) * HDIM;
            const f16* Vb = vt + (size_t)bh * HDIM * TT + (kt << 6);
#pragma unroll
            for (int i = 0; i < 4; i++) {
                int seg = tid + (i << 8);
                int krow = seg >> 4, kcol = (seg & 15) << 3;
                *(uint4*)&Ks[krow * 136 + kcol] = *(const uint4*)&Kb[(size_t)krow * HDIM + kcol];
                int vrow = seg >> 3, vcol = (seg & 7) << 3;
                *(uint4*)&Vs[vrow * 72 + vcol] = *(const uint4*)&Vb[(size_t)vrow * TT + vcol];
            }
            if (tid < 64) pbs[tid] = pb[b * TT + (kt << 6) + tid];
            __syncthreads();
            // S^T = K * Q^T : C-layout S^T[kv=quad*4+i][q=l16]
            floatx4 Sv[4];
#pragma unroll
            for (int mc = 0; mc < 4; mc++) Sv[mc] = (floatx4){0.f, 0.f, 0.f, 0.f};
#pragma unroll
            for (int kc = 0; kc < 4; kc++)
#pragma unroll
                for (int mc = 0; mc < 4; mc++) {
                    half8 kf = *(const half8*)&Ks[(mc * 16 + l16) * 136 + kc * 32 + (quad << 3)];
                    Sv[mc] = __builtin_amdgcn_mfma_f32_16x16x32_f16(kf, qf[kc], Sv[mc], 0, 0, 0);
                }
            // mask + bias + online softmax (per q column = per lane)
            float pv[4][4];
            float mnew = mx;
#pragma unroll
            for (int mc = 0; mc < 4; mc++) {
                float4 pbv = *(const float4*)&pbs[mc * 16 + (quad << 2)];
#pragma unroll
                for (int i = 0; i < 4; i++) {
                    int kv = (kt << 6) + mc * 16 + (quad << 2) + i;
                    float s = (kv <= qg) ? Sv[mc][i] + ((const float*)&pbv)[i] : -1e30f;
                    pv[mc][i] = s;
                    mnew = fmaxf(mnew, s);
                }
            }
            mnew = fmaxf(mnew, __shfl_xor(mnew, 16));
            mnew = fmaxf(mnew, __shfl_xor(mnew, 32));
            float al = __expf(mx - mnew);
            mx = mnew;
            float psum = 0.f;
#pragma unroll
            for (int mc = 0; mc < 4; mc++)
#pragma unroll
                for (int i = 0; i < 4; i++) {
                    float e = __expf(pv[mc][i] - mnew);
                    pv[mc][i] = e;
                    psum += e;
                }
            psum += __shfl_xor(psum, 16);
            psum += __shfl_xor(psum, 32);
            ls = ls * al + psum;
#pragma unroll
            for (int hm = 0; hm < 8; hm++)
#pragma unroll
                for (int i = 0; i < 4; i++) O[hm][i] *= al;
            // P^T as B-operand of 16x16x16 (k=quad*4+i == C rows). A = V^T.
            half4 pf[4];
#pragma unroll
            for (int mc = 0; mc < 4; mc++) {
                pf[mc][0] = (f16)pv[mc][0]; pf[mc][1] = (f16)pv[mc][1];
                pf[mc][2] = (f16)pv[mc][2]; pf[mc][3] = (f16)pv[mc][3];
            }
#pragma unroll
            for (int mc = 0; mc < 4; mc++)
#pragma unroll
                for (int hm = 0; hm < 8; hm++) {
                    half4 vf = *(const half4*)&Vs[(hm * 16 + l16) * 72 + mc * 16 + (quad << 2)];
                    O[hm] = __builtin_amdgcn_mfma_f32_16x16x16f16(vf, pf[mc], O[hm], 0, 0, 0);
                }
        }
        float inv = 1.0f / ls;
#pragma unroll
        for (int hm = 0; hm < 8; hm++) {
            half4 ov;
#pragma unroll
            for (int i = 0; i < 4; i++) ov[i] = (f16)(O[hm][i] * inv);
            *(half4*)&y[((size_t)b * TT + qg) * CCH + h * HDIM + hm * 16 + (quad << 2)] = ov;
        }
        __syncthreads();   // protect LDS before next pass restages
    }
}

extern "C" void kernel_launch(void* const* d_in, const int* in_sizes, int n_in,
                              void* d_out, int out_size, void* d_ws, size_t ws_size,
                              hipStream_t stream) {
    const float* x   = (const float*)d_in[0];
    const float* cs  = (const float*)d_in[1];
    const int*   tok = (const int*)d_in[2];
    const int*   pm  = (const int*)d_in[3];
    const float* Wa  = (const float*)d_in[4];
    const float* Wp  = (const float*)d_in[5];
    float* out = (float*)d_out;
    char* ws = (char*)d_ws;

    f16* x16 = (f16*)(ws + 0);             // 16 MB ; reused as y after GEMM1
    f16* WaT = (f16*)(ws + 16777216);      // 24 MB
    f16* vt  = (f16*)(ws + 41943040);      // 16 MB   [bh][hd][t]
    f16* WpT = (f16*)(ws + 58720256);      //  8 MB
    float2* tab = (float2*)(ws + 67108864);// 2 MB rope table (gap before qr)
    f16* qr  = (f16*)(ws + 92274688);      // 16 MB
    f16* kr  = (f16*)(ws + 109051904);     // 16 MB
    f16* vsc = (f16*)(ws + 125829120);     // 16 MB
    int*   cnt  = (int*)(ws + 142606336);  // 4 KB
    float* tpos = (float*)(ws + 142610432);// 16 KB
    float* pb   = (float*)(ws + 142626816);// 16 KB
    f16* y   = x16;

    hipMemsetAsync(cnt, 0, NBLK * sizeof(int), stream);
    k_hist<<<MM / 256, 256, 0, stream>>>(tok, cnt);
    k_scan<<<BB, TT, 0, stream>>>(tok, cnt, pm, tpos, pb);
    k_rope<<<MM * 64 / 256, 256, 0, stream>>>(tpos, tab);
    k_prep<<<dim3(N1 / 32, CCH / 32, 3), dim3(32, 8), 0, stream>>>(Wa, Wp, x, WaT, WpT, x16);
    k_gemm8<1><<<768, 512, 0, stream>>>(x16, WaT, nullptr, tab, cs, qr, kr, vsc);
    k_trv<<<dim3(4, 32, BB * HH), dim3(32, 8), 0, stream>>>(vsc, vt);
    k_attn<<<BB * HH * (NQT / 2), 256, 0, stream>>>(qr, kr, vt, pb, y);
    k_gemm8<0><<<256, 512, 0, stream>>>(y, WpT, out, nullptr, nullptr, nullptr, nullptr, nullptr);
}

// Round 9
// 371.127 us; speedup vs baseline: 1.0460x; 1.0460x over previous
//
#include <hip/hip_runtime.h>

#define BB 4
#define TT 1024
#define CCH 2048
#define HH 16
#define HDIM 128
#define NBLK 1024
#define MM (BB*TT)          // 4096
#define N1 (3*CCH)          // 6144
#define NQT 16              // T / 64

typedef _Float16 f16;
typedef _Float16 half8 __attribute__((ext_vector_type(8)));
typedef _Float16 half4 __attribute__((ext_vector_type(4)));
typedef float floatx4 __attribute__((ext_vector_type(4)));

// async global->LDS, 16B per lane. LDS dest = wave-uniform base + lane*16.
__device__ __forceinline__ void g2lds16(const void* g, void* l) {
    __builtin_amdgcn_global_load_lds((const __attribute__((address_space(1))) void*)g,
                                     (__attribute__((address_space(3))) void*)l, 16, 0, 0);
}

// ---- fused prep: z=0 transpose Wa -> WaT f16, z=1 Wp -> WpT, z=2 cvt x -> f16 ----
__global__ void k_prep(const float* __restrict__ Wa, const float* __restrict__ Wp,
                       const float* __restrict__ x,
                       f16* __restrict__ WaT, f16* __restrict__ WpT,
                       f16* __restrict__ x16) {
    int z = blockIdx.z;
    if (z == 2) {   // convert: MM*CCH/4 float4s
        int i = (blockIdx.y * 192 + blockIdx.x) * 256 + threadIdx.x + threadIdx.y * 32;
        if (i >= MM * CCH / 4) return;
        float4 v = ((const float4*)x)[i];
        union { ushort4 u; f16 h[4]; } o;
        o.h[0] = (f16)v.x; o.h[1] = (f16)v.y; o.h[2] = (f16)v.z; o.h[3] = (f16)v.w;
        ((ushort4*)x16)[i] = o.u;
        return;
    }
    const float* in = (z == 0) ? Wa : Wp;
    f16* out = (z == 0) ? WaT : WpT;
    int Cc = (z == 0) ? N1 : CCH;
    if (blockIdx.x * 32 >= Cc) return;
    __shared__ float tile[32][33];
    int c0 = blockIdx.x * 32, r0 = blockIdx.y * 32;
    int tx = threadIdx.x, ty = threadIdx.y;
#pragma unroll
    for (int k = 0; k < 4; k++) {
        int r = ty + k * 8;
        tile[r][tx] = in[(size_t)(r0 + r) * Cc + c0 + tx];
    }
    __syncthreads();
#pragma unroll
    for (int k = 0; k < 4; k++) {
        int r = ty + k * 8;
        out[(size_t)(c0 + r) * CCH + r0 + tx] = (f16)tile[tx][r];
    }
}

// ------- transpose f16 per-head [T][HD] -> [HD][T] (for V) -------
__global__ void k_trv(const f16* __restrict__ in, f16* __restrict__ out) {
    __shared__ f16 tile[32][34];
    int bh = blockIdx.z;
    int h0 = blockIdx.x * 32, t0 = blockIdx.y * 32;
    int tx = threadIdx.x, ty = threadIdx.y;
#pragma unroll
    for (int k = 0; k < 4; k++) {
        int t = ty + k * 8;
        tile[t][tx] = in[((size_t)bh * TT + t0 + t) * HDIM + h0 + tx];
    }
    __syncthreads();
#pragma unroll
    for (int k = 0; k < 4; k++) {
        int r = ty + k * 8;
        out[((size_t)bh * HDIM + h0 + r) * TT + t0 + tx] = tile[tx][r];
    }
}

// ---------------- global histogram over all B*T tokens ----------------
__global__ void k_hist(const int* __restrict__ tok, int* __restrict__ cnt) {
    int i = blockIdx.x * blockDim.x + threadIdx.x;
    if (i < MM) atomicAdd(cnt + tok[i], 1);
}

// ------- per-batch inclusive scan of 1/count; also padding bias -------
__global__ __launch_bounds__(1024) void k_scan(const int* __restrict__ tok,
                                               const int* __restrict__ cnt,
                                               const int* __restrict__ pm,
                                               float* __restrict__ tpos,
                                               float* __restrict__ pb) {
    __shared__ float s[TT];
    int b = blockIdx.x, t = threadIdx.x;
    s[t] = 1.0f / ((float)cnt[tok[b * TT + t]] + 1e-10f);
    __syncthreads();
    for (int off = 1; off < TT; off <<= 1) {
        float add = (t >= off) ? s[t - off] : 0.0f;
        __syncthreads();
        s[t] += add;
        __syncthreads();
    }
    tpos[b * TT + t] = s[t];
    pb[b * TT + t] = pm[b * TT + t] ? 0.0f : -1e30f;
}

// ------- rope table: tab[row*64+j] = (cos, sin) of tpos[row]*10000^(-j/64) -------
__global__ void k_rope(const float* __restrict__ tpos, float2* __restrict__ tab) {
    int i = blockIdx.x * 256 + threadIdx.x;     // MM*64 entries
    int row = i >> 6, j = i & 63;
    float f = tpos[row] * expf((float)j * -0.14391156929f);   // ln(10000)/64
    float sn, cn; sincosf(f, &sn, &cn);
    tab[i] = make_float2(cn, sn);
}

// ===== 256x128 GEMM, 8 waves x (64x64), BK=64, triple-buffered counted-vmcnt =====
// (round-8 best: 124us, MfmaUtil 35.5%, conflicts 0 — UNCHANGED this round)
#define BAR() __builtin_amdgcn_s_barrier()
#define RDA(S, base, ck) do { _Pragma("unroll") for (int m_ = 0; m_ < 4; m_++) \
    S[m_] = *(const half8*)((base) + aoffb + (m_ << 11) + (ck)); } while (0)
#define RDB(S, base, ck) do { _Pragma("unroll") for (int n_ = 0; n_ < 4; n_++) \
    S[n_] = *(const half8*)((base) + bofs[n_] + (ck)); } while (0)
#define STAGEA(t, base) do { _Pragma("unroll") for (int k_ = 0; k_ < 4; k_++) \
    g2lds16(Ab + (size_t)(k_ * 64) * 2048 + ((t) << 6) + srcr, \
            (base) + (w * 8 + k_ * 64) * 128); } while (0)
#define STAGEB(t, base) do { _Pragma("unroll") for (int k_ = 0; k_ < 2; k_++) \
    g2lds16(Bb + (size_t)(k_ * 64) * 2048 + ((t) << 6) + srcr, \
            (base) + (w * 8 + k_ * 64) * 128); } while (0)
#define MF16(SA, SB) do { _Pragma("unroll") for (int m_ = 0; m_ < 4; m_++) \
    _Pragma("unroll") for (int n_ = 0; n_ < 4; n_++) \
    acc[m_][n_] = __builtin_amdgcn_mfma_f32_16x16x32_f16(SA[m_], SB[n_], acc[m_][n_], 0, 0, 0); } while (0)

template <int MODE>   // 1: QKV fused rope epilogue (N=6144); 0: plain f32 C (N=2048)
__global__ __launch_bounds__(512, 2) void k_gemm8(const f16* __restrict__ A,
                                                  const f16* __restrict__ Bt,
                                                  float* __restrict__ Cp,
                                                  const float2* __restrict__ tab,
                                                  const float* __restrict__ cs,
                                                  f16* __restrict__ qr,
                                                  f16* __restrict__ kr,
                                                  f16* __restrict__ vsc) {
    const float SCALE = 0.08838834764831845f;   // 1/sqrt(128), folded into q
    const int NBN = MODE ? 48 : 16;
    const int NWG = MODE ? 768 : 256;
    const int CPX = NWG >> 3;
    __shared__ __align__(16) f16 As[3 * 16384];   // [3 buf][256][64], 96KB
    __shared__ __align__(16) f16 Bs[3 * 8192];    // [3 buf][128][64], 48KB

    int bid = blockIdx.x;
    int s = (bid & 7) * CPX + (bid >> 3);          // XCD swizzle (bijective: NWG%8==0)
    int bm = s / NBN, bn = s % NBN;

    int tid = threadIdx.x;
    int w = tid >> 6, lane = tid & 63, quad = lane >> 4, l16 = lane & 15;
    int wm = w & 3, wn = w >> 2;                   // 4 x 2 wave grid, 64x64 each

    const f16* Ab = A + (size_t)(bm << 8) * 2048;
    const f16* Bb = Bt + (size_t)(bn << 7) * 2048;

    // rotation-swizzle staging source: lane = (row rl, chunk cl); source chunk
    // (cl - row)&7 (row-block offsets are ==0 mod 8, so gl is row-invariant).
    int rl = lane >> 3, cl = lane & 7;
    int gl = (cl - rl) & 7;
    int srcr = (w * 8 + rl) * 2048 + gl * 8;

    // frag-read bases; read chunk (g + row)&7, row&7 == l16&7, g = kk*4 + quad.
    const int aoffb = (wm * 64 + l16) << 7;
    const int bofs[4] = { (wn * 32 + l16) << 7,        (wn * 32 + 64 + l16) << 7,
                          (wn * 32 + 16 + l16) << 7,   (wn * 32 + 80 + l16) << 7 };
    const int ck0 = ((quad + l16) & 7) << 4;
    const int ck1 = ck0 ^ 64;

    floatx4 acc[4][4];
#pragma unroll
    for (int i = 0; i < 4; i++)
#pragma unroll
        for (int j = 0; j < 4; j++) acc[i][j] = (floatx4){0.f, 0.f, 0.f, 0.f};

    half8 S0a[4], S1a[4];
    half8 S0b[4], S1b[4];

    char* a0 = (char*)As; char* a1 = a0 + 32768; char* a2 = a0 + 65536;
    char* b0 = (char*)Bs; char* b1 = b0 + 16384; char* b2 = b0 + 32768;

    // prologue: stage t0 -> buf0 (6 loads/wave), t1 -> buf1 (6)
    STAGEA(0, a0); STAGEB(0, b0);
    STAGEA(1, a1); STAGEB(1, b1);
    asm volatile("s_waitcnt vmcnt(6)" ::: "memory");   // t0 landed (t1 in flight)
    BAR();
    RDA(S0a, a0, ck0); RDB(S0b, b0, ck0);              // t0.kk0 -> S0

#pragma unroll 1
    for (int t = 0; t < 32; ++t) {
        // ph1: RD S1 <- cur.kk1; stage t+2 -> stg; MFMA t.kk0; counted vmcnt; BAR
        RDA(S1a, a0, ck1); RDB(S1b, b0, ck1);
        if (t + 2 < 32) { STAGEA(t + 2, a2); STAGEB(t + 2, b2); }
        __builtin_amdgcn_s_setprio(1); MF16(S0a, S0b); __builtin_amdgcn_s_setprio(0);
        if (t < 30) { asm volatile("s_waitcnt vmcnt(6)" ::: "memory"); }
        else        { asm volatile("s_waitcnt vmcnt(0)" ::: "memory"); }
        BAR();
        // ph2: RD S0 <- nxt.kk0; MFMA t.kk1; BAR
        if (t < 31) { RDA(S0a, a1, ck0); RDB(S0b, b1, ck0); }
        __builtin_amdgcn_s_setprio(1); MF16(S1a, S1b); __builtin_amdgcn_s_setprio(0);
        BAR();
        // rotate buffers: cur <- nxt <- stg <- cur
        char* ta = a0; a0 = a1; a1 = a2; a2 = ta;
        char* tb = b0; b0 = b1; b1 = b2; b2 = tb;
    }

    // ---- epilogue: rows = bm*256 + wm*64 + mf*16 + quad*4 + r
    //      cols = bn*128 + (nf&1)*64 + wn*32 + (nf>>1)*16 + l16
    if (MODE == 0) {
#pragma unroll
        for (int mf = 0; mf < 4; mf++)
#pragma unroll
            for (int nf = 0; nf < 4; nf++) {
                int col = (bn << 7) + ((nf & 1) << 6) + wn * 32 + ((nf >> 1) << 4) + l16;
#pragma unroll
                for (int r = 0; r < 4; r++) {
                    int row = (bm << 8) + wm * 64 + mf * 16 + (quad << 2) + r;
                    Cp[(size_t)row * CCH + col] = acc[mf][nf][r];
                }
            }
    } else {
        int type = bn >> 4;              // 0=q, 1=k, 2=v (16 blocks per 2048-col chunk)
        int h = bn & 15;                 // one head per block
        if (type < 2) {
            f16* outp = (type == 0) ? qr : kr;
#pragma unroll
            for (int mf = 0; mf < 4; mf++)
#pragma unroll
                for (int r = 0; r < 4; r++) {
                    int row = (bm << 8) + wm * 64 + mf * 16 + (quad << 2) + r;
#pragma unroll
                    for (int p = 0; p < 2; p++) {     // rope pairs: nf {0,1}, {2,3}
                        int d1 = wn * 32 + p * 16 + l16;   // 0..63
                        float2 tc = tab[row * 64 + d1];
                        float a1v = acc[mf][2 * p][r], a2v = acc[mf][2 * p + 1][r];
                        float o1 = a1v * tc.x - a2v * tc.y;
                        float o2 = a2v * tc.x + a1v * tc.y;
                        if (type == 0) {
                            if (d1 == 63) o2 = 1.0f;          // q[...,-1]=1 (before scale)
                            o1 *= SCALE; o2 *= SCALE;
                        } else {
                            if (d1 == 63) o2 = cs[row];       // k[...,-1]=cum_scores
                        }
                        size_t ob = ((size_t)((row >> 10) * HH + h) * TT + (row & 1023)) * HDIM + d1;
                        outp[ob] = (f16)o1;
                        outp[ob + 64] = (f16)o2;
                    }
                }
        } else {
#pragma unroll
            for (int mf = 0; mf < 4; mf++)
#pragma unroll
                for (int r = 0; r < 4; r++) {
                    int row = (bm << 8) + wm * 64 + mf * 16 + (quad << 2) + r;
                    float ve = __expf(cs[row]);
#pragma unroll
                    for (int nf = 0; nf < 4; nf++) {
                        int d = ((nf & 1) << 6) + wn * 32 + ((nf >> 1) << 4) + l16;
                        size_t ob = ((size_t)((row >> 10) * HH + h) * TT + (row & 1023)) * HDIM + d;
                        vsc[ob] = (f16)(acc[mf][nf][r] * ve);
                    }
                }
        }
    }
}

// ---------------- causal flash attention, S^T formulation ----------------
// ROUND-9: T14 async-stage split + double-buffered K/V/pbs LDS.
//   Old: per kv-iter {sync; stage (load->LDS, consumed immediately); sync;
//   compute} -> global-load latency (~200-900cy, KV set ~32MB ~ L2) exposed
//   serially 17x per block, 2 barriers/iter.
//   New: ping-pong buffers; issue kt+1's global loads into REGS before
//   computing kt; ds_write to the alternate buffer after PV; ONE sync/iter.
//   Latency hides under QK^T+softmax+PV (>1000cy). LDS 2x(17+18.4+0.25)KB
//   ~72KB -> still 2 blocks/CU. +32 VGPR held across compute (OK at 2 w/SIMD).
// Causal-mask hoist: kv<=qg can only fail when kt==qt (kv <= kt*64+63 <
//   qt*64 <= qg otherwise) -> per-element cmp only on the diagonal tile.
__global__ __launch_bounds__(256) void k_attn(const f16* __restrict__ qr,
                                              const f16* __restrict__ kr,
                                              const f16* __restrict__ vt,
                                              const float* __restrict__ pb,
                                              f16* __restrict__ y) {
    __shared__ __align__(16) f16 Ks[2][64 * 136];   // [kv][hd], pad 128->136
    __shared__ __align__(16) f16 Vs[2][128 * 72];   // [hd][kv], pad 64->72
    __shared__ float pbs[2][64];
    int p = blockIdx.x & (NQT / 2 - 1);
    int bh = blockIdx.x >> 3;
    int b = bh >> 4, h = bh & 15;
    int tid = threadIdx.x;
    int w = tid >> 6, lane = tid & 63, quad = lane >> 4, l16 = lane & 15;
    // per-thread staging indices (same for every tile)
    const int krow0 = tid >> 4, kcol0 = (tid & 15) << 3;     // + i*16 rows
    const int vrow0 = tid >> 3, vcol0 = (tid & 7) << 3;      // + i*32 rows
#pragma unroll
    for (int pass = 0; pass < 2; pass++) {
        int qt = pass ? (NQT - 1 - p) : p;
        int q0 = qt << 6;
        int qg = q0 + w * 16 + l16;                  // this lane's q column
        const f16* Qp = qr + ((size_t)bh * TT + qg) * HDIM;
        half8 qf[4];                                  // B-op: Q[q=l16][hd=kc*32+quad*8+e]
#pragma unroll
        for (int kc = 0; kc < 4; kc++) qf[kc] = *(const half8*)&Qp[kc * 32 + (quad << 3)];
        floatx4 O[8];                                 // O^T[hd][q] C-frags
#pragma unroll
        for (int i = 0; i < 8; i++) O[i] = (floatx4){0.f, 0.f, 0.f, 0.f};
        float mx = -1e30f, ls = 0.f;
        // ---- prologue: stage kv-tile 0 into buffer 0 (direct load->LDS)
        {
            const f16* Kb = kr + (size_t)bh * TT * HDIM;
            const f16* Vb = vt + (size_t)bh * HDIM * TT;
#pragma unroll
            for (int i = 0; i < 4; i++) {
                *(uint4*)&Ks[0][(krow0 + i * 16) * 136 + kcol0] =
                    *(const uint4*)&Kb[(size_t)(krow0 + i * 16) * HDIM + kcol0];
                *(uint4*)&Vs[0][(vrow0 + i * 32) * 72 + vcol0] =
                    *(const uint4*)&Vb[(size_t)(vrow0 + i * 32) * TT + vcol0];
            }
            if (tid < 64) pbs[0][tid] = pb[b * TT + tid];
        }
        __syncthreads();
        int cur = 0;
        for (int kt = 0; kt <= qt; kt++) {
            // ---- early-issue kt+1 loads into registers (latency hides under compute)
            uint4 kreg[4], vreg[4];
            float pbnext = 0.f;
            const bool have = (kt < qt);
            if (have) {
                const f16* Kb = kr + ((size_t)bh * TT + ((kt + 1) << 6)) * HDIM;
                const f16* Vb = vt + (size_t)bh * HDIM * TT + ((kt + 1) << 6);
#pragma unroll
                for (int i = 0; i < 4; i++) {
                    kreg[i] = *(const uint4*)&Kb[(size_t)(krow0 + i * 16) * HDIM + kcol0];
                    vreg[i] = *(const uint4*)&Vb[(size_t)(vrow0 + i * 32) * TT + vcol0];
                }
                if (tid < 64) pbnext = pb[b * TT + ((kt + 1) << 6) + tid];
            }
            const f16* Kl = Ks[cur];
            const f16* Vl = Vs[cur];
            // S^T = K * Q^T : C-layout S^T[kv=quad*4+i][q=l16]
            floatx4 Sv[4];
#pragma unroll
            for (int mc = 0; mc < 4; mc++) Sv[mc] = (floatx4){0.f, 0.f, 0.f, 0.f};
#pragma unroll
            for (int kc = 0; kc < 4; kc++)
#pragma unroll
                for (int mc = 0; mc < 4; mc++) {
                    half8 kf = *(const half8*)&Kl[(mc * 16 + l16) * 136 + kc * 32 + (quad << 3)];
                    Sv[mc] = __builtin_amdgcn_mfma_f32_16x16x32_f16(kf, qf[kc], Sv[mc], 0, 0, 0);
                }
            // bias + (diagonal-only) causal mask + online softmax (per q col = lane)
            float pv[4][4];
            float mnew = mx;
            if (kt == qt) {
#pragma unroll
                for (int mc = 0; mc < 4; mc++) {
                    float4 pbv = *(const float4*)&pbs[cur][mc * 16 + (quad << 2)];
#pragma unroll
                    for (int i = 0; i < 4; i++) {
                        int kv = (kt << 6) + mc * 16 + (quad << 2) + i;
                        float s = (kv <= qg) ? Sv[mc][i] + ((const float*)&pbv)[i] : -1e30f;
                        pv[mc][i] = s;
                        mnew = fmaxf(mnew, s);
                    }
                }
            } else {
#pragma unroll
                for (int mc = 0; mc < 4; mc++) {
                    float4 pbv = *(const float4*)&pbs[cur][mc * 16 + (quad << 2)];
#pragma unroll
                    for (int i = 0; i < 4; i++) {
                        float s = Sv[mc][i] + ((const float*)&pbv)[i];
                        pv[mc][i] = s;
                        mnew = fmaxf(mnew, s);
                    }
                }
            }
            mnew = fmaxf(mnew, __shfl_xor(mnew, 16));
            mnew = fmaxf(mnew, __shfl_xor(mnew, 32));
            float al = __expf(mx - mnew);
            mx = mnew;
            float psum = 0.f;
#pragma unroll
            for (int mc = 0; mc < 4; mc++)
#pragma unroll
                for (int i = 0; i < 4; i++) {
                    float e = __expf(pv[mc][i] - mnew);
                    pv[mc][i] = e;
                    psum += e;
                }
            psum += __shfl_xor(psum, 16);
            psum += __shfl_xor(psum, 32);
            ls = ls * al + psum;
#pragma unroll
            for (int hm = 0; hm < 8; hm++)
#pragma unroll
                for (int i = 0; i < 4; i++) O[hm][i] *= al;
            // P^T as B-operand of 16x16x16 (k=quad*4+i == C rows). A = V^T.
            half4 pf[4];
#pragma unroll
            for (int mc = 0; mc < 4; mc++) {
                pf[mc][0] = (f16)pv[mc][0]; pf[mc][1] = (f16)pv[mc][1];
                pf[mc][2] = (f16)pv[mc][2]; pf[mc][3] = (f16)pv[mc][3];
            }
#pragma unroll
            for (int mc = 0; mc < 4; mc++)
#pragma unroll
                for (int hm = 0; hm < 8; hm++) {
                    half4 vf = *(const half4*)&Vl[(hm * 16 + l16) * 72 + mc * 16 + (quad << 2)];
                    O[hm] = __builtin_amdgcn_mfma_f32_16x16x16f16(vf, pf[mc], O[hm], 0, 0, 0);
                }
            // ---- write staged kt+1 tile into the alternate buffer
            if (have) {
                int nxt = cur ^ 1;
#pragma unroll
                for (int i = 0; i < 4; i++) {
                    *(uint4*)&Ks[nxt][(krow0 + i * 16) * 136 + kcol0] = kreg[i];
                    *(uint4*)&Vs[nxt][(vrow0 + i * 32) * 72 + vcol0] = vreg[i];
                }
                if (tid < 64) pbs[nxt][tid] = pbnext;
            }
            __syncthreads();
            cur ^= 1;
        }
        float inv = 1.0f / ls;
#pragma unroll
        for (int hm = 0; hm < 8; hm++) {
            half4 ov;
#pragma unroll
            for (int i = 0; i < 4; i++) ov[i] = (f16)(O[hm][i] * inv);
            *(half4*)&y[((size_t)b * TT + qg) * CCH + h * HDIM + hm * 16 + (quad << 2)] = ov;
        }
        __syncthreads();   // protect LDS before next pass restages
    }
}

extern "C" void kernel_launch(void* const* d_in, const int* in_sizes, int n_in,
                              void* d_out, int out_size, void* d_ws, size_t ws_size,
                              hipStream_t stream) {
    const float* x   = (const float*)d_in[0];
    const float* cs  = (const float*)d_in[1];
    const int*   tok = (const int*)d_in[2];
    const int*   pm  = (const int*)d_in[3];
    const float* Wa  = (const float*)d_in[4];
    const float* Wp  = (const float*)d_in[5];
    float* out = (float*)d_out;
    char* ws = (char*)d_ws;

    f16* x16 = (f16*)(ws + 0);             // 16 MB ; reused as y after GEMM1
    f16* WaT = (f16*)(ws + 16777216);      // 24 MB
    f16* vt  = (f16*)(ws + 41943040);      // 16 MB   [bh][hd][t]
    f16* WpT = (f16*)(ws + 58720256);      //  8 MB
    float2* tab = (float2*)(ws + 67108864);// 2 MB rope table (gap before qr)
    f16* qr  = (f16*)(ws + 92274688);      // 16 MB
    f16* kr  = (f16*)(ws + 109051904);     // 16 MB
    f16* vsc = (f16*)(ws + 125829120);     // 16 MB
    int*   cnt  = (int*)(ws + 142606336);  // 4 KB
    float* tpos = (float*)(ws + 142610432);// 16 KB
    float* pb   = (float*)(ws + 142626816);// 16 KB
    f16* y   = x16;

    hipMemsetAsync(cnt, 0, NBLK * sizeof(int), stream);
    k_hist<<<MM / 256, 256, 0, stream>>>(tok, cnt);
    k_scan<<<BB, TT, 0, stream>>>(tok, cnt, pm, tpos, pb);
    k_rope<<<MM * 64 / 256, 256, 0, stream>>>(tpos, tab);
    k_prep<<<dim3(N1 / 32, CCH / 32, 3), dim3(32, 8), 0, stream>>>(Wa, Wp, x, WaT, WpT, x16);
    k_gemm8<1><<<768, 512, 0, stream>>>(x16, WaT, nullptr, tab, cs, qr, kr, vsc);
    k_trv<<<dim3(4, 32, BB * HH), dim3(32, 8), 0, stream>>>(vsc, vt);
    k_attn<<<BB * HH * (NQT / 2), 256, 0, stream>>>(qr, kr, vt, pb, y);
    k_gemm8<0><<<256, 512, 0, stream>>>(y, WpT, out, nullptr, nullptr, nullptr, nullptr, nullptr);
}

// Round 10
// 370.526 us; speedup vs baseline: 1.0477x; 1.0016x over previous
//
#include <hip/hip_runtime.h>

#define BB 4
#define TT 1024
#define CCH 2048
#define HH 16
#define HDIM 128
#define NBLK 1024
#define MM (BB*TT)          // 4096
#define N1 (3*CCH)          // 6144
#define NQT 16              // T / 64

typedef _Float16 f16;
typedef _Float16 half8 __attribute__((ext_vector_type(8)));
typedef _Float16 half4 __attribute__((ext_vector_type(4)));
typedef float floatx4 __attribute__((ext_vector_type(4)));

// async global->LDS, 16B per lane. LDS dest = wave-uniform base + lane*16.
__device__ __forceinline__ void g2lds16(const void* g, void* l) {
    __builtin_amdgcn_global_load_lds((const __attribute__((address_space(1))) void*)g,
                                     (__attribute__((address_space(3))) void*)l, 16, 0, 0);
}

// ---- fused prep: z=0 transpose Wa -> WaT f16, z=1 Wp -> WpT, z=2 cvt x -> f16 ----
__global__ void k_prep(const float* __restrict__ Wa, const float* __restrict__ Wp,
                       const float* __restrict__ x,
                       f16* __restrict__ WaT, f16* __restrict__ WpT,
                       f16* __restrict__ x16) {
    int z = blockIdx.z;
    if (z == 2) {   // convert: MM*CCH/4 float4s
        int i = (blockIdx.y * 192 + blockIdx.x) * 256 + threadIdx.x + threadIdx.y * 32;
        if (i >= MM * CCH / 4) return;
        float4 v = ((const float4*)x)[i];
        union { ushort4 u; f16 h[4]; } o;
        o.h[0] = (f16)v.x; o.h[1] = (f16)v.y; o.h[2] = (f16)v.z; o.h[3] = (f16)v.w;
        ((ushort4*)x16)[i] = o.u;
        return;
    }
    const float* in = (z == 0) ? Wa : Wp;
    f16* out = (z == 0) ? WaT : WpT;
    int Cc = (z == 0) ? N1 : CCH;
    if (blockIdx.x * 32 >= Cc) return;
    __shared__ float tile[32][33];
    int c0 = blockIdx.x * 32, r0 = blockIdx.y * 32;
    int tx = threadIdx.x, ty = threadIdx.y;
#pragma unroll
    for (int k = 0; k < 4; k++) {
        int r = ty + k * 8;
        tile[r][tx] = in[(size_t)(r0 + r) * Cc + c0 + tx];
    }
    __syncthreads();
#pragma unroll
    for (int k = 0; k < 4; k++) {
        int r = ty + k * 8;
        out[(size_t)(c0 + r) * CCH + r0 + tx] = (f16)tile[tx][r];
    }
}

// ------- transpose f16 per-head [T][HD] -> [HD][T] (for V) -------
__global__ void k_trv(const f16* __restrict__ in, f16* __restrict__ out) {
    __shared__ f16 tile[32][34];
    int bh = blockIdx.z;
    int h0 = blockIdx.x * 32, t0 = blockIdx.y * 32;
    int tx = threadIdx.x, ty = threadIdx.y;
#pragma unroll
    for (int k = 0; k < 4; k++) {
        int t = ty + k * 8;
        tile[t][tx] = in[((size_t)bh * TT + t0 + t) * HDIM + h0 + tx];
    }
    __syncthreads();
#pragma unroll
    for (int k = 0; k < 4; k++) {
        int r = ty + k * 8;
        out[((size_t)bh * HDIM + h0 + r) * TT + t0 + tx] = tile[tx][r];
    }
}

// ---------------- global histogram over all B*T tokens ----------------
__global__ void k_hist(const int* __restrict__ tok, int* __restrict__ cnt) {
    int i = blockIdx.x * blockDim.x + threadIdx.x;
    if (i < MM) atomicAdd(cnt + tok[i], 1);
}

// ------- per-batch inclusive scan of 1/count; also padding bias -------
__global__ __launch_bounds__(1024) void k_scan(const int* __restrict__ tok,
                                               const int* __restrict__ cnt,
                                               const int* __restrict__ pm,
                                               float* __restrict__ tpos,
                                               float* __restrict__ pb) {
    __shared__ float s[TT];
    int b = blockIdx.x, t = threadIdx.x;
    s[t] = 1.0f / ((float)cnt[tok[b * TT + t]] + 1e-10f);
    __syncthreads();
    for (int off = 1; off < TT; off <<= 1) {
        float add = (t >= off) ? s[t - off] : 0.0f;
        __syncthreads();
        s[t] += add;
        __syncthreads();
    }
    tpos[b * TT + t] = s[t];
    pb[b * TT + t] = pm[b * TT + t] ? 0.0f : -1e30f;
}

// ------- rope table: tab[row*64+j] = (cos, sin) of tpos[row]*10000^(-j/64) -------
__global__ void k_rope(const float* __restrict__ tpos, float2* __restrict__ tab) {
    int i = blockIdx.x * 256 + threadIdx.x;     // MM*64 entries
    int row = i >> 6, j = i & 63;
    float f = tpos[row] * expf((float)j * -0.14391156929f);   // ln(10000)/64
    float sn, cn; sincosf(f, &sn, &cn);
    tab[i] = make_float2(cn, sn);
}

// ==== 128x128 GEMM, 4 waves x (64x64), BK=64, dbuf, 2 blocks/CU (TLP fix) ====
// ROUND-10: three schedule variants (r5 32%, r7 34%, r8 35.5%) plateaued at
//   ~0.5x the port ceiling with ONE block/CU — 8-wave lockstep: the whole CU
//   idles at each barrier/vmcnt. m97 (128^2, 3 blocks/CU) hit 37%/912TF via
//   cross-block async overlap (m114). Fix: halve the tile -> 64KB LDS ->
//   2 blocks/CU, KEEPING r8's 64x64 wave geometry (port ceiling 81%) and
//   r5's proven 2-phase reg-prefetch schedule + rotation swizzle verbatim.
// Grids exact: GEMM1 32x48=1536 = 3.0 rounds of 512 resident; GEMM2 512 = 1.0.
// Pipeline per K-tile t (2 phases, 1 barrier each; cur=a0/b0, nxt=a1/b1):
//   ph1: RD S1<-cur.kk1; MFMA S0 (t.kk0); vmcnt(0) [t+1 landed, 2-phase
//        flight ~1400cy >= HBM ~900cy]; BAR
//   ph2: RD S0<-nxt.kk0; STAGE t+2 -> cur (WAR: cur fully read in ph1,
//        separated by BAR — r5's proven pattern); MFMA S1 (t.kk1); BAR; swap
#define BAR() __builtin_amdgcn_s_barrier()
#define RDA(S, base, ck) do { _Pragma("unroll") for (int m_ = 0; m_ < 4; m_++) \
    S[m_] = *(const half8*)((base) + aoffb + (m_ << 11) + (ck)); } while (0)
#define RDB(S, base, ck) do { _Pragma("unroll") for (int n_ = 0; n_ < 4; n_++) \
    S[n_] = *(const half8*)((base) + bofs[n_] + (ck)); } while (0)
#define STAGEA(t, base) do { _Pragma("unroll") for (int k_ = 0; k_ < 4; k_++) \
    g2lds16(Ab + (size_t)(k_ * 32) * 2048 + ((t) << 6) + srcr, \
            (base) + (w * 8 + k_ * 32) * 128); } while (0)
#define STAGEB(t, base) do { _Pragma("unroll") for (int k_ = 0; k_ < 4; k_++) \
    g2lds16(Bb + (size_t)(k_ * 32) * 2048 + ((t) << 6) + srcr, \
            (base) + (w * 8 + k_ * 32) * 128); } while (0)
#define MF16(SA, SB) do { _Pragma("unroll") for (int m_ = 0; m_ < 4; m_++) \
    _Pragma("unroll") for (int n_ = 0; n_ < 4; n_++) \
    acc[m_][n_] = __builtin_amdgcn_mfma_f32_16x16x32_f16(SA[m_], SB[n_], acc[m_][n_], 0, 0, 0); } while (0)

template <int MODE>   // 1: QKV fused rope epilogue (N=6144); 0: plain f32 C (N=2048)
__global__ __launch_bounds__(256, 2) void k_gemm8(const f16* __restrict__ A,
                                                  const f16* __restrict__ Bt,
                                                  float* __restrict__ Cp,
                                                  const float2* __restrict__ tab,
                                                  const float* __restrict__ cs,
                                                  f16* __restrict__ qr,
                                                  f16* __restrict__ kr,
                                                  f16* __restrict__ vsc) {
    const float SCALE = 0.08838834764831845f;   // 1/sqrt(128), folded into q
    const int NBN = MODE ? 48 : 16;
    const int NWG = MODE ? 1536 : 512;
    const int CPX = NWG >> 3;
    __shared__ __align__(16) f16 As[2 * 8192];    // [2 buf][128][64], 32KB
    __shared__ __align__(16) f16 Bs[2 * 8192];    // [2 buf][128][64], 32KB

    int bid = blockIdx.x;
    int s = (bid & 7) * CPX + (bid >> 3);          // XCD swizzle (bijective: NWG%8==0)
    int bm = s / NBN, bn = s % NBN;

    int tid = threadIdx.x;
    int w = tid >> 6, lane = tid & 63, quad = lane >> 4, l16 = lane & 15;
    int wm = w & 1, wn = w >> 1;                   // 2 x 2 wave grid, 64x64 each

    const f16* Ab = A + (size_t)(bm << 7) * 2048;
    const f16* Bb = Bt + (size_t)(bn << 7) * 2048;

    // rotation-swizzle staging source: lane = (row rl, chunk cl); source chunk
    // (cl - row)&7 (row-block offsets are ==0 mod 8, so gl is row-invariant).
    int rl = lane >> 3, cl = lane & 7;
    int gl = (cl - rl) & 7;
    int srcr = (w * 8 + rl) * 2048 + gl * 8;       // waves cover 32 rows/chunk

    // frag-read bases; read chunk (g + row)&7, row&7 == l16&7, g = kk*4 + quad.
    const int aoffb = (wm * 64 + l16) << 7;
    const int bofs[4] = { (wn * 32 + l16) << 7,        (wn * 32 + 64 + l16) << 7,
                          (wn * 32 + 16 + l16) << 7,   (wn * 32 + 80 + l16) << 7 };
    const int ck0 = ((quad + l16) & 7) << 4;
    const int ck1 = ck0 ^ 64;

    floatx4 acc[4][4];
#pragma unroll
    for (int i = 0; i < 4; i++)
#pragma unroll
        for (int j = 0; j < 4; j++) acc[i][j] = (floatx4){0.f, 0.f, 0.f, 0.f};

    half8 S0a[4], S1a[4];
    half8 S0b[4], S1b[4];

    char* a0 = (char*)As; char* a1 = a0 + 16384;
    char* b0 = (char*)Bs; char* b1 = b0 + 16384;

    // prologue: stage t0 -> buf0 (8 loads/wave), t1 -> buf1 (8)
    STAGEA(0, a0); STAGEB(0, b0);
    STAGEA(1, a1); STAGEB(1, b1);
    asm volatile("s_waitcnt vmcnt(8)" ::: "memory");   // t0 landed (t1 in flight)
    BAR();
    RDA(S0a, a0, ck0); RDB(S0b, b0, ck0);              // t0.kk0 -> S0

#pragma unroll 1
    for (int t = 0; t < 32; ++t) {
        // ph1: RD S1 <- cur.kk1; MFMA t.kk0; vmcnt(0) (t+1 landed); BAR
        RDA(S1a, a0, ck1); RDB(S1b, b0, ck1);
        __builtin_amdgcn_s_setprio(1); MF16(S0a, S0b); __builtin_amdgcn_s_setprio(0);
        asm volatile("s_waitcnt vmcnt(0)" ::: "memory");
        BAR();
        // ph2: RD S0 <- nxt.kk0; STAGE t+2 -> cur; MFMA t.kk1; BAR; swap
        if (t < 31) { RDA(S0a, a1, ck0); RDB(S0b, b1, ck0); }
        if (t + 2 < 32) { STAGEA(t + 2, a0); STAGEB(t + 2, b0); }
        __builtin_amdgcn_s_setprio(1); MF16(S1a, S1b); __builtin_amdgcn_s_setprio(0);
        BAR();
        char* ta = a0; a0 = a1; a1 = ta;
        char* tb = b0; b0 = b1; b1 = tb;
    }

    // ---- epilogue: rows = bm*128 + wm*64 + mf*16 + quad*4 + r
    //      cols = bn*128 + (nf&1)*64 + wn*32 + (nf>>1)*16 + l16
    if (MODE == 0) {
#pragma unroll
        for (int mf = 0; mf < 4; mf++)
#pragma unroll
            for (int nf = 0; nf < 4; nf++) {
                int col = (bn << 7) + ((nf & 1) << 6) + wn * 32 + ((nf >> 1) << 4) + l16;
#pragma unroll
                for (int r = 0; r < 4; r++) {
                    int row = (bm << 7) + wm * 64 + mf * 16 + (quad << 2) + r;
                    Cp[(size_t)row * CCH + col] = acc[mf][nf][r];
                }
            }
    } else {
        int type = bn >> 4;              // 0=q, 1=k, 2=v (16 blocks per 2048-col chunk)
        int h = bn & 15;                 // one head per block
        if (type < 2) {
            f16* outp = (type == 0) ? qr : kr;
#pragma unroll
            for (int mf = 0; mf < 4; mf++)
#pragma unroll
                for (int r = 0; r < 4; r++) {
                    int row = (bm << 7) + wm * 64 + mf * 16 + (quad << 2) + r;
#pragma unroll
                    for (int p = 0; p < 2; p++) {     // rope pairs: nf {0,1}, {2,3}
                        int d1 = wn * 32 + p * 16 + l16;   // 0..63
                        float2 tc = tab[row * 64 + d1];
                        float a1v = acc[mf][2 * p][r], a2v = acc[mf][2 * p + 1][r];
                        float o1 = a1v * tc.x - a2v * tc.y;
                        float o2 = a2v * tc.x + a1v * tc.y;
                        if (type == 0) {
                            if (d1 == 63) o2 = 1.0f;          // q[...,-1]=1 (before scale)
                            o1 *= SCALE; o2 *= SCALE;
                        } else {
                            if (d1 == 63) o2 = cs[row];       // k[...,-1]=cum_scores
                        }
                        size_t ob = ((size_t)((row >> 10) * HH + h) * TT + (row & 1023)) * HDIM + d1;
                        outp[ob] = (f16)o1;
                        outp[ob + 64] = (f16)o2;
                    }
                }
        } else {
#pragma unroll
            for (int mf = 0; mf < 4; mf++)
#pragma unroll
                for (int r = 0; r < 4; r++) {
                    int row = (bm << 7) + wm * 64 + mf * 16 + (quad << 2) + r;
                    float ve = __expf(cs[row]);
#pragma unroll
                    for (int nf = 0; nf < 4; nf++) {
                        int d = ((nf & 1) << 6) + wn * 32 + ((nf >> 1) << 4) + l16;
                        size_t ob = ((size_t)((row >> 10) * HH + h) * TT + (row & 1023)) * HDIM + d;
                        vsc[ob] = (f16)(acc[mf][nf][r] * ve);
                    }
                }
        }
    }
}

// ---------------- causal flash attention, S^T formulation ----------------
// (round-9: T14 async-stage + dbuf K/V + diagonal-only mask — UNCHANGED)
__global__ __launch_bounds__(256) void k_attn(const f16* __restrict__ qr,
                                              const f16* __restrict__ kr,
                                              const f16* __restrict__ vt,
                                              const float* __restrict__ pb,
                                              f16* __restrict__ y) {
    __shared__ __align__(16) f16 Ks[2][64 * 136];   // [kv][hd], pad 128->136
    __shared__ __align__(16) f16 Vs[2][128 * 72];   // [hd][kv], pad 64->72
    __shared__ float pbs[2][64];
    int p = blockIdx.x & (NQT / 2 - 1);
    int bh = blockIdx.x >> 3;
    int b = bh >> 4, h = bh & 15;
    int tid = threadIdx.x;
    int w = tid >> 6, lane = tid & 63, quad = lane >> 4, l16 = lane & 15;
    const int krow0 = tid >> 4, kcol0 = (tid & 15) << 3;     // + i*16 rows
    const int vrow0 = tid >> 3, vcol0 = (tid & 7) << 3;      // + i*32 rows
#pragma unroll
    for (int pass = 0; pass < 2; pass++) {
        int qt = pass ? (NQT - 1 - p) : p;
        int q0 = qt << 6;
        int qg = q0 + w * 16 + l16;                  // this lane's q column
        const f16* Qp = qr + ((size_t)bh * TT + qg) * HDIM;
        half8 qf[4];                                  // B-op: Q[q=l16][hd=kc*32+quad*8+e]
#pragma unroll
        for (int kc = 0; kc < 4; kc++) qf[kc] = *(const half8*)&Qp[kc * 32 + (quad << 3)];
        floatx4 O[8];                                 // O^T[hd][q] C-frags
#pragma unroll
        for (int i = 0; i < 8; i++) O[i] = (floatx4){0.f, 0.f, 0.f, 0.f};
        float mx = -1e30f, ls = 0.f;
        {
            const f16* Kb = kr + (size_t)bh * TT * HDIM;
            const f16* Vb = vt + (size_t)bh * HDIM * TT;
#pragma unroll
            for (int i = 0; i < 4; i++) {
                *(uint4*)&Ks[0][(krow0 + i * 16) * 136 + kcol0] =
                    *(const uint4*)&Kb[(size_t)(krow0 + i * 16) * HDIM + kcol0];
                *(uint4*)&Vs[0][(vrow0 + i * 32) * 72 + vcol0] =
                    *(const uint4*)&Vb[(size_t)(vrow0 + i * 32) * TT + vcol0];
            }
            if (tid < 64) pbs[0][tid] = pb[b * TT + tid];
        }
        __syncthreads();
        int cur = 0;
        for (int kt = 0; kt <= qt; kt++) {
            uint4 kreg[4], vreg[4];
            float pbnext = 0.f;
            const bool have = (kt < qt);
            if (have) {
                const f16* Kb = kr + ((size_t)bh * TT + ((kt + 1) << 6)) * HDIM;
                const f16* Vb = vt + (size_t)bh * HDIM * TT + ((kt + 1) << 6);
#pragma unroll
                for (int i = 0; i < 4; i++) {
                    kreg[i] = *(const uint4*)&Kb[(size_t)(krow0 + i * 16) * HDIM + kcol0];
                    vreg[i] = *(const uint4*)&Vb[(size_t)(vrow0 + i * 32) * TT + vcol0];
                }
                if (tid < 64) pbnext = pb[b * TT + ((kt + 1) << 6) + tid];
            }
            const f16* Kl = Ks[cur];
            const f16* Vl = Vs[cur];
            floatx4 Sv[4];
#pragma unroll
            for (int mc = 0; mc < 4; mc++) Sv[mc] = (floatx4){0.f, 0.f, 0.f, 0.f};
#pragma unroll
            for (int kc = 0; kc < 4; kc++)
#pragma unroll
                for (int mc = 0; mc < 4; mc++) {
                    half8 kf = *(const half8*)&Kl[(mc * 16 + l16) * 136 + kc * 32 + (quad << 3)];
                    Sv[mc] = __builtin_amdgcn_mfma_f32_16x16x32_f16(kf, qf[kc], Sv[mc], 0, 0, 0);
                }
            float pv[4][4];
            float mnew = mx;
            if (kt == qt) {
#pragma unroll
                for (int mc = 0; mc < 4; mc++) {
                    float4 pbv = *(const float4*)&pbs[cur][mc * 16 + (quad << 2)];
#pragma unroll
                    for (int i = 0; i < 4; i++) {
                        int kv = (kt << 6) + mc * 16 + (quad << 2) + i;
                        float s = (kv <= qg) ? Sv[mc][i] + ((const float*)&pbv)[i] : -1e30f;
                        pv[mc][i] = s;
                        mnew = fmaxf(mnew, s);
                    }
                }
            } else {
#pragma unroll
                for (int mc = 0; mc < 4; mc++) {
                    float4 pbv = *(const float4*)&pbs[cur][mc * 16 + (quad << 2)];
#pragma unroll
                    for (int i = 0; i < 4; i++) {
                        float s = Sv[mc][i] + ((const float*)&pbv)[i];
                        pv[mc][i] = s;
                        mnew = fmaxf(mnew, s);
                    }
                }
            }
            mnew = fmaxf(mnew, __shfl_xor(mnew, 16));
            mnew = fmaxf(mnew, __shfl_xor(mnew, 32));
            float al = __expf(mx - mnew);
            mx = mnew;
            float psum = 0.f;
#pragma unroll
            for (int mc = 0; mc < 4; mc++)
#pragma unroll
                for (int i = 0; i < 4; i++) {
                    float e = __expf(pv[mc][i] - mnew);
                    pv[mc][i] = e;
                    psum += e;
                }
            psum += __shfl_xor(psum, 16);
            psum += __shfl_xor(psum, 32);
            ls = ls * al + psum;
#pragma unroll
            for (int hm = 0; hm < 8; hm++)
#pragma unroll
                for (int i = 0; i < 4; i++) O[hm][i] *= al;
            half4 pf[4];
#pragma unroll
            for (int mc = 0; mc < 4; mc++) {
                pf[mc][0] = (f16)pv[mc][0]; pf[mc][1] = (f16)pv[mc][1];
                pf[mc][2] = (f16)pv[mc][2]; pf[mc][3] = (f16)pv[mc][3];
            }
#pragma unroll
            for (int mc = 0; mc < 4; mc++)
#pragma unroll
                for (int hm = 0; hm < 8; hm++) {
                    half4 vf = *(const half4*)&Vl[(hm * 16 + l16) * 72 + mc * 16 + (quad << 2)];
                    O[hm] = __builtin_amdgcn_mfma_f32_16x16x16f16(vf, pf[mc], O[hm], 0, 0, 0);
                }
            if (have) {
                int nxt = cur ^ 1;
#pragma unroll
                for (int i = 0; i < 4; i++) {
                    *(uint4*)&Ks[nxt][(krow0 + i * 16) * 136 + kcol0] = kreg[i];
                    *(uint4*)&Vs[nxt][(vrow0 + i * 32) * 72 + vcol0] = vreg[i];
                }
                if (tid < 64) pbs[nxt][tid] = pbnext;
            }
            __syncthreads();
            cur ^= 1;
        }
        float inv = 1.0f / ls;
#pragma unroll
        for (int hm = 0; hm < 8; hm++) {
            half4 ov;
#pragma unroll
            for (int i = 0; i < 4; i++) ov[i] = (f16)(O[hm][i] * inv);
            *(half4*)&y[((size_t)b * TT + qg) * CCH + h * HDIM + hm * 16 + (quad << 2)] = ov;
        }
        __syncthreads();   // protect LDS before next pass restages
    }
}

extern "C" void kernel_launch(void* const* d_in, const int* in_sizes, int n_in,
                              void* d_out, int out_size, void* d_ws, size_t ws_size,
                              hipStream_t stream) {
    const float* x   = (const float*)d_in[0];
    const float* cs  = (const float*)d_in[1];
    const int*   tok = (const int*)d_in[2];
    const int*   pm  = (const int*)d_in[3];
    const float* Wa  = (const float*)d_in[4];
    const float* Wp  = (const float*)d_in[5];
    float* out = (float*)d_out;
    char* ws = (char*)d_ws;

    f16* x16 = (f16*)(ws + 0);             // 16 MB ; reused as y after GEMM1
    f16* WaT = (f16*)(ws + 16777216);      // 24 MB
    f16* vt  = (f16*)(ws + 41943040);      // 16 MB   [bh][hd][t]
    f16* WpT = (f16*)(ws + 58720256);      //  8 MB
    float2* tab = (float2*)(ws + 67108864);// 2 MB rope table (gap before qr)
    f16* qr  = (f16*)(ws + 92274688);      // 16 MB
    f16* kr  = (f16*)(ws + 109051904);     // 16 MB
    f16* vsc = (f16*)(ws + 125829120);     // 16 MB
    int*   cnt  = (int*)(ws + 142606336);  // 4 KB
    float* tpos = (float*)(ws + 142610432);// 16 KB
    float* pb   = (float*)(ws + 142626816);// 16 KB
    f16* y   = x16;

    hipMemsetAsync(cnt, 0, NBLK * sizeof(int), stream);
    k_hist<<<MM / 256, 256, 0, stream>>>(tok, cnt);
    k_scan<<<BB, TT, 0, stream>>>(tok, cnt, pm, tpos, pb);
    k_rope<<<MM * 64 / 256, 256, 0, stream>>>(tpos, tab);
    k_prep<<<dim3(N1 / 32, CCH / 32, 3), dim3(32, 8), 0, stream>>>(Wa, Wp, x, WaT, WpT, x16);
    k_gemm8<1><<<1536, 256, 0, stream>>>(x16, WaT, nullptr, tab, cs, qr, kr, vsc);
    k_trv<<<dim3(4, 32, BB * HH), dim3(32, 8), 0, stream>>>(vsc, vt);
    k_attn<<<BB * HH * (NQT / 2), 256, 0, stream>>>(qr, kr, vt, pb, y);
    k_gemm8<0><<<512, 256, 0, stream>>>(y, WpT, out, nullptr, nullptr, nullptr, nullptr, nullptr);
}

// Round 11
// 364.771 us; speedup vs baseline: 1.0642x; 1.0158x over previous
//
#include <hip/hip_runtime.h>

#define BB 4
#define TT 1024
#define CCH 2048
#define HH 16
#define HDIM 128
#define NBLK 1024
#define MM (BB*TT)          // 4096
#define N1 (3*CCH)          // 6144
#define NQT 16              // T / 64

typedef _Float16 f16;
typedef _Float16 half8 __attribute__((ext_vector_type(8)));
typedef _Float16 half4 __attribute__((ext_vector_type(4)));
typedef float floatx4 __attribute__((ext_vector_type(4)));

// async global->LDS, 16B per lane. LDS dest = wave-uniform base + lane*16.
__device__ __forceinline__ void g2lds16(const void* g, void* l) {
    __builtin_amdgcn_global_load_lds((const __attribute__((address_space(1))) void*)g,
                                     (__attribute__((address_space(3))) void*)l, 16, 0, 0);
}

// ---- fused prep: z=0 transpose Wa -> WaT f16, z=1 Wp -> WpT, z=2 cvt x -> f16 ----
// ROUND-11: 64x64 transpose tiles, f16-in-LDS ([64][34] pad -> ushort2 gathers
// conflict-free: bank stride 17 mod 32), ushort2 (4B) writes -> 128B segments
// per 32 lanes (was 32 f16 = 64B half-line segments on 48MB of writes).
__global__ void k_prep(const float* __restrict__ Wa, const float* __restrict__ Wp,
                       const float* __restrict__ x,
                       f16* __restrict__ WaT, f16* __restrict__ WpT,
                       f16* __restrict__ x16) {
    int z = blockIdx.z;
    int tx = threadIdx.x, ty = threadIdx.y;
    if (z == 2) {   // convert: MM*CCH/4 float4s, 2 per thread (grid 192x32)
        int base = (blockIdx.y * 192 + blockIdx.x) * 256 + ty * 32 + tx;
#pragma unroll
        for (int q = 0; q < 2; q++) {
            int i = base + q * (192 * 32 * 256);
            if (i < MM * CCH / 4) {
                float4 v = ((const float4*)x)[i];
                union { ushort4 u; f16 h[4]; } o;
                o.h[0] = (f16)v.x; o.h[1] = (f16)v.y; o.h[2] = (f16)v.z; o.h[3] = (f16)v.w;
                ((ushort4*)x16)[i] = o.u;
            }
        }
        return;
    }
    const float* in = (z == 0) ? Wa : Wp;
    f16* out = (z == 0) ? WaT : WpT;
    int Cc = (z == 0) ? N1 : CCH;
    if (blockIdx.x * 32 >= Cc) return;
    __shared__ f16 tile[64][34];
    int c0 = blockIdx.x * 32, r0 = blockIdx.y * 64;
#pragma unroll
    for (int k = 0; k < 8; k++) {
        int r = ty + k * 8;
        tile[r][tx] = (f16)in[(size_t)(r0 + r) * Cc + c0 + tx];
    }
    __syncthreads();
#pragma unroll
    for (int k = 0; k < 4; k++) {
        int c = ty + k * 8;
        union { ushort2 u; f16 h[2]; } o2;
        o2.h[0] = tile[2 * tx][c];
        o2.h[1] = tile[2 * tx + 1][c];
        *(ushort2*)&out[(size_t)(c0 + c) * CCH + r0 + 2 * tx] = o2.u;
    }
}

// ---------------- global histogram over all B*T tokens ----------------
__global__ void k_hist(const int* __restrict__ tok, int* __restrict__ cnt) {
    int i = blockIdx.x * blockDim.x + threadIdx.x;
    if (i < MM) atomicAdd(cnt + tok[i], 1);
}

// ------- per-batch inclusive scan of 1/count; also padding bias -------
__global__ __launch_bounds__(1024) void k_scan(const int* __restrict__ tok,
                                               const int* __restrict__ cnt,
                                               const int* __restrict__ pm,
                                               float* __restrict__ tpos,
                                               float* __restrict__ pb) {
    __shared__ float s[TT];
    int b = blockIdx.x, t = threadIdx.x;
    s[t] = 1.0f / ((float)cnt[tok[b * TT + t]] + 1e-10f);
    __syncthreads();
    for (int off = 1; off < TT; off <<= 1) {
        float add = (t >= off) ? s[t - off] : 0.0f;
        __syncthreads();
        s[t] += add;
        __syncthreads();
    }
    tpos[b * TT + t] = s[t];
    pb[b * TT + t] = pm[b * TT + t] ? 0.0f : -1e30f;
}

// ------- rope table: tab[row*64+j] = (cos, sin) of tpos[row]*10000^(-j/64) -------
__global__ void k_rope(const float* __restrict__ tpos, float2* __restrict__ tab) {
    int i = blockIdx.x * 256 + threadIdx.x;     // MM*64 entries
    int row = i >> 6, j = i & 63;
    float f = tpos[row] * expf((float)j * -0.14391156929f);   // ln(10000)/64
    float sn, cn; sincosf(f, &sn, &cn);
    tab[i] = make_float2(cn, sn);
}

// ===== 256x128 GEMM, 8 waves x (64x64), BK=64, triple-buffered counted-vmcnt =====
// (round-8 best: 124us, MfmaUtil 35.5%, conflicts 0. ROUND-11 change: the V
//  epilogue writes vt TRANSPOSED directly ([bh][hd][t], half4 of 4 consecutive
//  t) — deletes the separate k_trv kernel (32MB traffic + launch).)
#define BAR() __builtin_amdgcn_s_barrier()
#define RDA(S, base, ck) do { _Pragma("unroll") for (int m_ = 0; m_ < 4; m_++) \
    S[m_] = *(const half8*)((base) + aoffb + (m_ << 11) + (ck)); } while (0)
#define RDB(S, base, ck) do { _Pragma("unroll") for (int n_ = 0; n_ < 4; n_++) \
    S[n_] = *(const half8*)((base) + bofs[n_] + (ck)); } while (0)
#define STAGEA(t, base) do { _Pragma("unroll") for (int k_ = 0; k_ < 4; k_++) \
    g2lds16(Ab + (size_t)(k_ * 64) * 2048 + ((t) << 6) + srcr, \
            (base) + (w * 8 + k_ * 64) * 128); } while (0)
#define STAGEB(t, base) do { _Pragma("unroll") for (int k_ = 0; k_ < 2; k_++) \
    g2lds16(Bb + (size_t)(k_ * 64) * 2048 + ((t) << 6) + srcr, \
            (base) + (w * 8 + k_ * 64) * 128); } while (0)
#define MF16(SA, SB) do { _Pragma("unroll") for (int m_ = 0; m_ < 4; m_++) \
    _Pragma("unroll") for (int n_ = 0; n_ < 4; n_++) \
    acc[m_][n_] = __builtin_amdgcn_mfma_f32_16x16x32_f16(SA[m_], SB[n_], acc[m_][n_], 0, 0, 0); } while (0)

template <int MODE>   // 1: QKV fused rope epilogue (N=6144); 0: plain f32 C (N=2048)
__global__ __launch_bounds__(512, 2) void k_gemm8(const f16* __restrict__ A,
                                                  const f16* __restrict__ Bt,
                                                  float* __restrict__ Cp,
                                                  const float2* __restrict__ tab,
                                                  const float* __restrict__ cs,
                                                  f16* __restrict__ qr,
                                                  f16* __restrict__ kr,
                                                  f16* __restrict__ vsc) {
    const float SCALE = 0.08838834764831845f;   // 1/sqrt(128), folded into q
    const int NBN = MODE ? 48 : 16;
    const int NWG = MODE ? 768 : 256;
    const int CPX = NWG >> 3;
    __shared__ __align__(16) f16 As[3 * 16384];   // [3 buf][256][64], 96KB
    __shared__ __align__(16) f16 Bs[3 * 8192];    // [3 buf][128][64], 48KB

    int bid = blockIdx.x;
    int s = (bid & 7) * CPX + (bid >> 3);          // XCD swizzle (bijective: NWG%8==0)
    int bm = s / NBN, bn = s % NBN;

    int tid = threadIdx.x;
    int w = tid >> 6, lane = tid & 63, quad = lane >> 4, l16 = lane & 15;
    int wm = w & 3, wn = w >> 2;                   // 4 x 2 wave grid, 64x64 each

    const f16* Ab = A + (size_t)(bm << 8) * 2048;
    const f16* Bb = Bt + (size_t)(bn << 7) * 2048;

    // rotation-swizzle staging source: lane = (row rl, chunk cl); source chunk
    // (cl - row)&7 (row-block offsets are ==0 mod 8, so gl is row-invariant).
    int rl = lane >> 3, cl = lane & 7;
    int gl = (cl - rl) & 7;
    int srcr = (w * 8 + rl) * 2048 + gl * 8;

    // frag-read bases; read chunk (g + row)&7, row&7 == l16&7, g = kk*4 + quad.
    const int aoffb = (wm * 64 + l16) << 7;
    const int bofs[4] = { (wn * 32 + l16) << 7,        (wn * 32 + 64 + l16) << 7,
                          (wn * 32 + 16 + l16) << 7,   (wn * 32 + 80 + l16) << 7 };
    const int ck0 = ((quad + l16) & 7) << 4;
    const int ck1 = ck0 ^ 64;

    floatx4 acc[4][4];
#pragma unroll
    for (int i = 0; i < 4; i++)
#pragma unroll
        for (int j = 0; j < 4; j++) acc[i][j] = (floatx4){0.f, 0.f, 0.f, 0.f};

    half8 S0a[4], S1a[4];
    half8 S0b[4], S1b[4];

    char* a0 = (char*)As; char* a1 = a0 + 32768; char* a2 = a0 + 65536;
    char* b0 = (char*)Bs; char* b1 = b0 + 16384; char* b2 = b0 + 32768;

    // prologue: stage t0 -> buf0 (6 loads/wave), t1 -> buf1 (6)
    STAGEA(0, a0); STAGEB(0, b0);
    STAGEA(1, a1); STAGEB(1, b1);
    asm volatile("s_waitcnt vmcnt(6)" ::: "memory");   // t0 landed (t1 in flight)
    BAR();
    RDA(S0a, a0, ck0); RDB(S0b, b0, ck0);              // t0.kk0 -> S0

#pragma unroll 1
    for (int t = 0; t < 32; ++t) {
        // ph1: RD S1 <- cur.kk1; stage t+2 -> stg; MFMA t.kk0; counted vmcnt; BAR
        RDA(S1a, a0, ck1); RDB(S1b, b0, ck1);
        if (t + 2 < 32) { STAGEA(t + 2, a2); STAGEB(t + 2, b2); }
        __builtin_amdgcn_s_setprio(1); MF16(S0a, S0b); __builtin_amdgcn_s_setprio(0);
        if (t < 30) { asm volatile("s_waitcnt vmcnt(6)" ::: "memory"); }
        else        { asm volatile("s_waitcnt vmcnt(0)" ::: "memory"); }
        BAR();
        // ph2: RD S0 <- nxt.kk0; MFMA t.kk1; BAR
        if (t < 31) { RDA(S0a, a1, ck0); RDB(S0b, b1, ck0); }
        __builtin_amdgcn_s_setprio(1); MF16(S1a, S1b); __builtin_amdgcn_s_setprio(0);
        BAR();
        // rotate buffers: cur <- nxt <- stg <- cur
        char* ta = a0; a0 = a1; a1 = a2; a2 = ta;
        char* tb = b0; b0 = b1; b1 = b2; b2 = tb;
    }

    // ---- epilogue: rows = bm*256 + wm*64 + mf*16 + quad*4 + r
    //      cols = bn*128 + (nf&1)*64 + wn*32 + (nf>>1)*16 + l16
    if (MODE == 0) {
#pragma unroll
        for (int mf = 0; mf < 4; mf++)
#pragma unroll
            for (int nf = 0; nf < 4; nf++) {
                int col = (bn << 7) + ((nf & 1) << 6) + wn * 32 + ((nf >> 1) << 4) + l16;
#pragma unroll
                for (int r = 0; r < 4; r++) {
                    int row = (bm << 8) + wm * 64 + mf * 16 + (quad << 2) + r;
                    Cp[(size_t)row * CCH + col] = acc[mf][nf][r];
                }
            }
    } else {
        int type = bn >> 4;              // 0=q, 1=k, 2=v (16 blocks per 2048-col chunk)
        int h = bn & 15;                 // one head per block
        if (type < 2) {
            f16* outp = (type == 0) ? qr : kr;
#pragma unroll
            for (int mf = 0; mf < 4; mf++)
#pragma unroll
                for (int r = 0; r < 4; r++) {
                    int row = (bm << 8) + wm * 64 + mf * 16 + (quad << 2) + r;
#pragma unroll
                    for (int p = 0; p < 2; p++) {     // rope pairs: nf {0,1}, {2,3}
                        int d1 = wn * 32 + p * 16 + l16;   // 0..63
                        float2 tc = tab[row * 64 + d1];
                        float a1v = acc[mf][2 * p][r], a2v = acc[mf][2 * p + 1][r];
                        float o1 = a1v * tc.x - a2v * tc.y;
                        float o2 = a2v * tc.x + a1v * tc.y;
                        if (type == 0) {
                            if (d1 == 63) o2 = 1.0f;          // q[...,-1]=1 (before scale)
                            o1 *= SCALE; o2 *= SCALE;
                        } else {
                            if (d1 == 63) o2 = cs[row];       // k[...,-1]=cum_scores
                        }
                        size_t ob = ((size_t)((row >> 10) * HH + h) * TT + (row & 1023)) * HDIM + d1;
                        outp[ob] = (f16)o1;
                        outp[ob + 64] = (f16)o2;
                    }
                }
        } else {
            // V: write vt TRANSPOSED directly: vt[bh][d][t], half4 over 4 consecutive t
#pragma unroll
            for (int mf = 0; mf < 4; mf++) {
                int row0 = (bm << 8) + wm * 64 + mf * 16 + (quad << 2);
                float4 cs4 = *(const float4*)&cs[row0];
                float ve[4];
                ve[0] = __expf(cs4.x); ve[1] = __expf(cs4.y);
                ve[2] = __expf(cs4.z); ve[3] = __expf(cs4.w);
                size_t bhbase = (size_t)((row0 >> 10) * HH + h) * HDIM;
                int t0 = row0 & 1023;
#pragma unroll
                for (int nf = 0; nf < 4; nf++) {
                    int d = ((nf & 1) << 6) + wn * 32 + ((nf >> 1) << 4) + l16;
                    half4 ov;
#pragma unroll
                    for (int r = 0; r < 4; r++) ov[r] = (f16)(acc[mf][nf][r] * ve[r]);
                    *(half4*)&vsc[(bhbase + d) * TT + t0] = ov;
                }
            }
        }
    }
}

// ---------------- causal flash attention, S^T formulation ----------------
// (round-9: T14 async-stage + dbuf K/V + diagonal-only mask — UNCHANGED)
__global__ __launch_bounds__(256) void k_attn(const f16* __restrict__ qr,
                                              const f16* __restrict__ kr,
                                              const f16* __restrict__ vt,
                                              const float* __restrict__ pb,
                                              f16* __restrict__ y) {
    __shared__ __align__(16) f16 Ks[2][64 * 136];   // [kv][hd], pad 128->136
    __shared__ __align__(16) f16 Vs[2][128 * 72];   // [hd][kv], pad 64->72
    __shared__ float pbs[2][64];
    int p = blockIdx.x & (NQT / 2 - 1);
    int bh = blockIdx.x >> 3;
    int b = bh >> 4, h = bh & 15;
    int tid = threadIdx.x;
    int w = tid >> 6, lane = tid & 63, quad = lane >> 4, l16 = lane & 15;
    const int krow0 = tid >> 4, kcol0 = (tid & 15) << 3;     // + i*16 rows
    const int vrow0 = tid >> 3, vcol0 = (tid & 7) << 3;      // + i*32 rows
#pragma unroll
    for (int pass = 0; pass < 2; pass++) {
        int qt = pass ? (NQT - 1 - p) : p;
        int q0 = qt << 6;
        int qg = q0 + w * 16 + l16;                  // this lane's q column
        const f16* Qp = qr + ((size_t)bh * TT + qg) * HDIM;
        half8 qf[4];                                  // B-op: Q[q=l16][hd=kc*32+quad*8+e]
#pragma unroll
        for (int kc = 0; kc < 4; kc++) qf[kc] = *(const half8*)&Qp[kc * 32 + (quad << 3)];
        floatx4 O[8];                                 // O^T[hd][q] C-frags
#pragma unroll
        for (int i = 0; i < 8; i++) O[i] = (floatx4){0.f, 0.f, 0.f, 0.f};
        float mx = -1e30f, ls = 0.f;
        {
            const f16* Kb = kr + (size_t)bh * TT * HDIM;
            const f16* Vb = vt + (size_t)bh * HDIM * TT;
#pragma unroll
            for (int i = 0; i < 4; i++) {
                *(uint4*)&Ks[0][(krow0 + i * 16) * 136 + kcol0] =
                    *(const uint4*)&Kb[(size_t)(krow0 + i * 16) * HDIM + kcol0];
                *(uint4*)&Vs[0][(vrow0 + i * 32) * 72 + vcol0] =
                    *(const uint4*)&Vb[(size_t)(vrow0 + i * 32) * TT + vcol0];
            }
            if (tid < 64) pbs[0][tid] = pb[b * TT + tid];
        }
        __syncthreads();
        int cur = 0;
        for (int kt = 0; kt <= qt; kt++) {
            uint4 kreg[4], vreg[4];
            float pbnext = 0.f;
            const bool have = (kt < qt);
            if (have) {
                const f16* Kb = kr + ((size_t)bh * TT + ((kt + 1) << 6)) * HDIM;
                const f16* Vb = vt + (size_t)bh * HDIM * TT + ((kt + 1) << 6);
#pragma unroll
                for (int i = 0; i < 4; i++) {
                    kreg[i] = *(const uint4*)&Kb[(size_t)(krow0 + i * 16) * HDIM + kcol0];
                    vreg[i] = *(const uint4*)&Vb[(size_t)(vrow0 + i * 32) * TT + vcol0];
                }
                if (tid < 64) pbnext = pb[b * TT + ((kt + 1) << 6) + tid];
            }
            const f16* Kl = Ks[cur];
            const f16* Vl = Vs[cur];
            floatx4 Sv[4];
#pragma unroll
            for (int mc = 0; mc < 4; mc++) Sv[mc] = (floatx4){0.f, 0.f, 0.f, 0.f};
#pragma unroll
            for (int kc = 0; kc < 4; kc++)
#pragma unroll
                for (int mc = 0; mc < 4; mc++) {
                    half8 kf = *(const half8*)&Kl[(mc * 16 + l16) * 136 + kc * 32 + (quad << 3)];
                    Sv[mc] = __builtin_amdgcn_mfma_f32_16x16x32_f16(kf, qf[kc], Sv[mc], 0, 0, 0);
                }
            float pv[4][4];
            float mnew = mx;
            if (kt == qt) {
#pragma unroll
                for (int mc = 0; mc < 4; mc++) {
                    float4 pbv = *(const float4*)&pbs[cur][mc * 16 + (quad << 2)];
#pragma unroll
                    for (int i = 0; i < 4; i++) {
                        int kv = (kt << 6) + mc * 16 + (quad << 2) + i;
                        float s = (kv <= qg) ? Sv[mc][i] + ((const float*)&pbv)[i] : -1e30f;
                        pv[mc][i] = s;
                        mnew = fmaxf(mnew, s);
                    }
                }
            } else {
#pragma unroll
                for (int mc = 0; mc < 4; mc++) {
                    float4 pbv = *(const float4*)&pbs[cur][mc * 16 + (quad << 2)];
#pragma unroll
                    for (int i = 0; i < 4; i++) {
                        float s = Sv[mc][i] + ((const float*)&pbv)[i];
                        pv[mc][i] = s;
                        mnew = fmaxf(mnew, s);
                    }
                }
            }
            mnew = fmaxf(mnew, __shfl_xor(mnew, 16));
            mnew = fmaxf(mnew, __shfl_xor(mnew, 32));
            float al = __expf(mx - mnew);
            mx = mnew;
            float psum = 0.f;
#pragma unroll
            for (int mc = 0; mc < 4; mc++)
#pragma unroll
                for (int i = 0; i < 4; i++) {
                    float e = __expf(pv[mc][i] - mnew);
                    pv[mc][i] = e;
                    psum += e;
                }
            psum += __shfl_xor(psum, 16);
            psum += __shfl_xor(psum, 32);
            ls = ls * al + psum;
#pragma unroll
            for (int hm = 0; hm < 8; hm++)
#pragma unroll
                for (int i = 0; i < 4; i++) O[hm][i] *= al;
            half4 pf[4];
#pragma unroll
            for (int mc = 0; mc < 4; mc++) {
                pf[mc][0] = (f16)pv[mc][0]; pf[mc][1] = (f16)pv[mc][1];
                pf[mc][2] = (f16)pv[mc][2]; pf[mc][3] = (f16)pv[mc][3];
            }
#pragma unroll
            for (int mc = 0; mc < 4; mc++)
#pragma unroll
                for (int hm = 0; hm < 8; hm++) {
                    half4 vf = *(const half4*)&Vl[(hm * 16 + l16) * 72 + mc * 16 + (quad << 2)];
                    O[hm] = __builtin_amdgcn_mfma_f32_16x16x16f16(vf, pf[mc], O[hm], 0, 0, 0);
                }
            if (have) {
                int nxt = cur ^ 1;
#pragma unroll
                for (int i = 0; i < 4; i++) {
                    *(uint4*)&Ks[nxt][(krow0 + i * 16) * 136 + kcol0] = kreg[i];
                    *(uint4*)&Vs[nxt][(vrow0 + i * 32) * 72 + vcol0] = vreg[i];
                }
                if (tid < 64) pbs[nxt][tid] = pbnext;
            }
            __syncthreads();
            cur ^= 1;
        }
        float inv = 1.0f / ls;
#pragma unroll
        for (int hm = 0; hm < 8; hm++) {
            half4 ov;
#pragma unroll
            for (int i = 0; i < 4; i++) ov[i] = (f16)(O[hm][i] * inv);
            *(half4*)&y[((size_t)b * TT + qg) * CCH + h * HDIM + hm * 16 + (quad << 2)] = ov;
        }
        __syncthreads();   // protect LDS before next pass restages
    }
}

extern "C" void kernel_launch(void* const* d_in, const int* in_sizes, int n_in,
                              void* d_out, int out_size, void* d_ws, size_t ws_size,
                              hipStream_t stream) {
    const float* x   = (const float*)d_in[0];
    const float* cs  = (const float*)d_in[1];
    const int*   tok = (const int*)d_in[2];
    const int*   pm  = (const int*)d_in[3];
    const float* Wa  = (const float*)d_in[4];
    const float* Wp  = (const float*)d_in[5];
    float* out = (float*)d_out;
    char* ws = (char*)d_ws;

    f16* x16 = (f16*)(ws + 0);             // 16 MB ; reused as y after GEMM1
    f16* WaT = (f16*)(ws + 16777216);      // 24 MB
    f16* vt  = (f16*)(ws + 41943040);      // 16 MB   [bh][hd][t] (written by GEMM1)
    f16* WpT = (f16*)(ws + 58720256);      //  8 MB
    float2* tab = (float2*)(ws + 67108864);// 2 MB rope table (gap before qr)
    f16* qr  = (f16*)(ws + 92274688);      // 16 MB
    f16* kr  = (f16*)(ws + 109051904);     // 16 MB
    int*   cnt  = (int*)(ws + 142606336);  // 4 KB
    float* tpos = (float*)(ws + 142610432);// 16 KB
    float* pb   = (float*)(ws + 142626816);// 16 KB
    f16* y   = x16;

    hipMemsetAsync(cnt, 0, NBLK * sizeof(int), stream);
    k_hist<<<MM / 256, 256, 0, stream>>>(tok, cnt);
    k_scan<<<BB, TT, 0, stream>>>(tok, cnt, pm, tpos, pb);
    k_rope<<<MM * 64 / 256, 256, 0, stream>>>(tpos, tab);
    k_prep<<<dim3(192, 32, 3), dim3(32, 8), 0, stream>>>(Wa, Wp, x, WaT, WpT, x16);
    k_gemm8<1><<<768, 512, 0, stream>>>(x16, WaT, nullptr, tab, cs, qr, kr, vt);
    k_attn<<<BB * HH * (NQT / 2), 256, 0, stream>>>(qr, kr, vt, pb, y);
    k_gemm8<0><<<256, 512, 0, stream>>>(y, WpT, out, nullptr, nullptr, nullptr, nullptr, nullptr);
}

// Round 12
// 361.208 us; speedup vs baseline: 1.0747x; 1.0099x over previous
//
#include <hip/hip_runtime.h>

#define BB 4
#define TT 1024
#define CCH 2048
#define HH 16
#define HDIM 128
#define NBLK 1024
#define MM (BB*TT)          // 4096
#define N1 (3*CCH)          // 6144
#define NQT 16              // T / 64

typedef _Float16 f16;
typedef _Float16 half8 __attribute__((ext_vector_type(8)));
typedef _Float16 half4 __attribute__((ext_vector_type(4)));
typedef float floatx4 __attribute__((ext_vector_type(4)));

// async global->LDS, 16B per lane. LDS dest = wave-uniform base + lane*16.
__device__ __forceinline__ void g2lds16(const void* g, void* l) {
    __builtin_amdgcn_global_load_lds((const __attribute__((address_space(1))) void*)g,
                                     (__attribute__((address_space(3))) void*)l, 16, 0, 0);
}

// ---- fused prep: z=0 transpose Wa -> WaT f16, z=1 Wp -> WpT, z=2 cvt x -> f16 ----
__global__ void k_prep(const float* __restrict__ Wa, const float* __restrict__ Wp,
                       const float* __restrict__ x,
                       f16* __restrict__ WaT, f16* __restrict__ WpT,
                       f16* __restrict__ x16) {
    int z = blockIdx.z;
    int tx = threadIdx.x, ty = threadIdx.y;
    if (z == 2) {   // convert: MM*CCH/4 float4s, 2 per thread (grid 192x32)
        int base = (blockIdx.y * 192 + blockIdx.x) * 256 + ty * 32 + tx;
#pragma unroll
        for (int q = 0; q < 2; q++) {
            int i = base + q * (192 * 32 * 256);
            if (i < MM * CCH / 4) {
                float4 v = ((const float4*)x)[i];
                union { ushort4 u; f16 h[4]; } o;
                o.h[0] = (f16)v.x; o.h[1] = (f16)v.y; o.h[2] = (f16)v.z; o.h[3] = (f16)v.w;
                ((ushort4*)x16)[i] = o.u;
            }
        }
        return;
    }
    const float* in = (z == 0) ? Wa : Wp;
    f16* out = (z == 0) ? WaT : WpT;
    int Cc = (z == 0) ? N1 : CCH;
    if (blockIdx.x * 32 >= Cc) return;
    __shared__ f16 tile[64][34];
    int c0 = blockIdx.x * 32, r0 = blockIdx.y * 64;
#pragma unroll
    for (int k = 0; k < 8; k++) {
        int r = ty + k * 8;
        tile[r][tx] = (f16)in[(size_t)(r0 + r) * Cc + c0 + tx];
    }
    __syncthreads();
#pragma unroll
    for (int k = 0; k < 4; k++) {
        int c = ty + k * 8;
        union { ushort2 u; f16 h[2]; } o2;
        o2.h[0] = tile[2 * tx][c];
        o2.h[1] = tile[2 * tx + 1][c];
        *(ushort2*)&out[(size_t)(c0 + c) * CCH + r0 + 2 * tx] = o2.u;
    }
}

// ---------------- global histogram over all B*T tokens ----------------
__global__ void k_hist(const int* __restrict__ tok, int* __restrict__ cnt) {
    int i = blockIdx.x * blockDim.x + threadIdx.x;
    if (i < MM) atomicAdd(cnt + tok[i], 1);
}

// ------- per-batch inclusive scan of 1/count; also padding bias -------
__global__ __launch_bounds__(1024) void k_scan(const int* __restrict__ tok,
                                               const int* __restrict__ cnt,
                                               const int* __restrict__ pm,
                                               float* __restrict__ tpos,
                                               float* __restrict__ pb) {
    __shared__ float s[TT];
    int b = blockIdx.x, t = threadIdx.x;
    s[t] = 1.0f / ((float)cnt[tok[b * TT + t]] + 1e-10f);
    __syncthreads();
    for (int off = 1; off < TT; off <<= 1) {
        float add = (t >= off) ? s[t - off] : 0.0f;
        __syncthreads();
        s[t] += add;
        __syncthreads();
    }
    tpos[b * TT + t] = s[t];
    pb[b * TT + t] = pm[b * TT + t] ? 0.0f : -1e30f;
}

// ------- rope table: tab[row*64+j] = (cos, sin) of tpos[row]*10000^(-j/64) -------
__global__ void k_rope(const float* __restrict__ tpos, float2* __restrict__ tab) {
    int i = blockIdx.x * 256 + threadIdx.x;     // MM*64 entries
    int row = i >> 6, j = i & 63;
    float f = tpos[row] * expf((float)j * -0.14391156929f);   // ln(10000)/64
    float sn, cn; sincosf(f, &sn, &cn);
    tab[i] = make_float2(cn, sn);
}

// ===== 256x128 GEMM, 8 waves x (64x64), BK=64, triple-buffered counted-vmcnt =====
// (round-8 best: 124us, MfmaUtil 35.5%, conflicts 0. V epilogue writes vt
//  transposed directly — UNCHANGED from round 11.)
#define BAR() __builtin_amdgcn_s_barrier()
#define RDA(S, base, ck) do { _Pragma("unroll") for (int m_ = 0; m_ < 4; m_++) \
    S[m_] = *(const half8*)((base) + aoffb + (m_ << 11) + (ck)); } while (0)
#define RDB(S, base, ck) do { _Pragma("unroll") for (int n_ = 0; n_ < 4; n_++) \
    S[n_] = *(const half8*)((base) + bofs[n_] + (ck)); } while (0)
#define STAGEA(t, base) do { _Pragma("unroll") for (int k_ = 0; k_ < 4; k_++) \
    g2lds16(Ab + (size_t)(k_ * 64) * 2048 + ((t) << 6) + srcr, \
            (base) + (w * 8 + k_ * 64) * 128); } while (0)
#define STAGEB(t, base) do { _Pragma("unroll") for (int k_ = 0; k_ < 2; k_++) \
    g2lds16(Bb + (size_t)(k_ * 64) * 2048 + ((t) << 6) + srcr, \
            (base) + (w * 8 + k_ * 64) * 128); } while (0)
#define MF16(SA, SB) do { _Pragma("unroll") for (int m_ = 0; m_ < 4; m_++) \
    _Pragma("unroll") for (int n_ = 0; n_ < 4; n_++) \
    acc[m_][n_] = __builtin_amdgcn_mfma_f32_16x16x32_f16(SA[m_], SB[n_], acc[m_][n_], 0, 0, 0); } while (0)

template <int MODE>   // 1: QKV fused rope epilogue (N=6144); 0: plain f32 C (N=2048)
__global__ __launch_bounds__(512, 2) void k_gemm8(const f16* __restrict__ A,
                                                  const f16* __restrict__ Bt,
                                                  float* __restrict__ Cp,
                                                  const float2* __restrict__ tab,
                                                  const float* __restrict__ cs,
                                                  f16* __restrict__ qr,
                                                  f16* __restrict__ kr,
                                                  f16* __restrict__ vsc) {
    const float SCALE = 0.08838834764831845f;   // 1/sqrt(128), folded into q
    const int NBN = MODE ? 48 : 16;
    const int NWG = MODE ? 768 : 256;
    const int CPX = NWG >> 3;
    __shared__ __align__(16) f16 As[3 * 16384];   // [3 buf][256][64], 96KB
    __shared__ __align__(16) f16 Bs[3 * 8192];    // [3 buf][128][64], 48KB

    int bid = blockIdx.x;
    int s = (bid & 7) * CPX + (bid >> 3);          // XCD swizzle (bijective: NWG%8==0)
    int bm = s / NBN, bn = s % NBN;

    int tid = threadIdx.x;
    int w = tid >> 6, lane = tid & 63, quad = lane >> 4, l16 = lane & 15;
    int wm = w & 3, wn = w >> 2;                   // 4 x 2 wave grid, 64x64 each

    const f16* Ab = A + (size_t)(bm << 8) * 2048;
    const f16* Bb = Bt + (size_t)(bn << 7) * 2048;

    int rl = lane >> 3, cl = lane & 7;
    int gl = (cl - rl) & 7;
    int srcr = (w * 8 + rl) * 2048 + gl * 8;

    const int aoffb = (wm * 64 + l16) << 7;
    const int bofs[4] = { (wn * 32 + l16) << 7,        (wn * 32 + 64 + l16) << 7,
                          (wn * 32 + 16 + l16) << 7,   (wn * 32 + 80 + l16) << 7 };
    const int ck0 = ((quad + l16) & 7) << 4;
    const int ck1 = ck0 ^ 64;

    floatx4 acc[4][4];
#pragma unroll
    for (int i = 0; i < 4; i++)
#pragma unroll
        for (int j = 0; j < 4; j++) acc[i][j] = (floatx4){0.f, 0.f, 0.f, 0.f};

    half8 S0a[4], S1a[4];
    half8 S0b[4], S1b[4];

    char* a0 = (char*)As; char* a1 = a0 + 32768; char* a2 = a0 + 65536;
    char* b0 = (char*)Bs; char* b1 = b0 + 16384; char* b2 = b0 + 32768;

    STAGEA(0, a0); STAGEB(0, b0);
    STAGEA(1, a1); STAGEB(1, b1);
    asm volatile("s_waitcnt vmcnt(6)" ::: "memory");   // t0 landed (t1 in flight)
    BAR();
    RDA(S0a, a0, ck0); RDB(S0b, b0, ck0);              // t0.kk0 -> S0

#pragma unroll 1
    for (int t = 0; t < 32; ++t) {
        RDA(S1a, a0, ck1); RDB(S1b, b0, ck1);
        if (t + 2 < 32) { STAGEA(t + 2, a2); STAGEB(t + 2, b2); }
        __builtin_amdgcn_s_setprio(1); MF16(S0a, S0b); __builtin_amdgcn_s_setprio(0);
        if (t < 30) { asm volatile("s_waitcnt vmcnt(6)" ::: "memory"); }
        else        { asm volatile("s_waitcnt vmcnt(0)" ::: "memory"); }
        BAR();
        if (t < 31) { RDA(S0a, a1, ck0); RDB(S0b, b1, ck0); }
        __builtin_amdgcn_s_setprio(1); MF16(S1a, S1b); __builtin_amdgcn_s_setprio(0);
        BAR();
        char* ta = a0; a0 = a1; a1 = a2; a2 = ta;
        char* tb = b0; b0 = b1; b1 = b2; b2 = tb;
    }

    if (MODE == 0) {
#pragma unroll
        for (int mf = 0; mf < 4; mf++)
#pragma unroll
            for (int nf = 0; nf < 4; nf++) {
                int col = (bn << 7) + ((nf & 1) << 6) + wn * 32 + ((nf >> 1) << 4) + l16;
#pragma unroll
                for (int r = 0; r < 4; r++) {
                    int row = (bm << 8) + wm * 64 + mf * 16 + (quad << 2) + r;
                    Cp[(size_t)row * CCH + col] = acc[mf][nf][r];
                }
            }
    } else {
        int type = bn >> 4;              // 0=q, 1=k, 2=v (16 blocks per 2048-col chunk)
        int h = bn & 15;                 // one head per block
        if (type < 2) {
            f16* outp = (type == 0) ? qr : kr;
#pragma unroll
            for (int mf = 0; mf < 4; mf++)
#pragma unroll
                for (int r = 0; r < 4; r++) {
                    int row = (bm << 8) + wm * 64 + mf * 16 + (quad << 2) + r;
#pragma unroll
                    for (int p = 0; p < 2; p++) {     // rope pairs: nf {0,1}, {2,3}
                        int d1 = wn * 32 + p * 16 + l16;   // 0..63
                        float2 tc = tab[row * 64 + d1];
                        float a1v = acc[mf][2 * p][r], a2v = acc[mf][2 * p + 1][r];
                        float o1 = a1v * tc.x - a2v * tc.y;
                        float o2 = a2v * tc.x + a1v * tc.y;
                        if (type == 0) {
                            if (d1 == 63) o2 = 1.0f;          // q[...,-1]=1 (before scale)
                            o1 *= SCALE; o2 *= SCALE;
                        } else {
                            if (d1 == 63) o2 = cs[row];       // k[...,-1]=cum_scores
                        }
                        size_t ob = ((size_t)((row >> 10) * HH + h) * TT + (row & 1023)) * HDIM + d1;
                        outp[ob] = (f16)o1;
                        outp[ob + 64] = (f16)o2;
                    }
                }
        } else {
            // V: write vt TRANSPOSED directly: vt[bh][d][t], half4 over 4 consecutive t
#pragma unroll
            for (int mf = 0; mf < 4; mf++) {
                int row0 = (bm << 8) + wm * 64 + mf * 16 + (quad << 2);
                float4 cs4 = *(const float4*)&cs[row0];
                float ve[4];
                ve[0] = __expf(cs4.x); ve[1] = __expf(cs4.y);
                ve[2] = __expf(cs4.z); ve[3] = __expf(cs4.w);
                size_t bhbase = (size_t)((row0 >> 10) * HH + h) * HDIM;
                int t0 = row0 & 1023;
#pragma unroll
                for (int nf = 0; nf < 4; nf++) {
                    int d = ((nf & 1) << 6) + wn * 32 + ((nf >> 1) << 4) + l16;
                    half4 ov;
#pragma unroll
                    for (int r = 0; r < 4; r++) ov[r] = (f16)(acc[mf][nf][r] * ve[r]);
                    *(half4*)&vsc[(bhbase + d) * TT + t0] = ov;
                }
            }
        }
    }
}

// ---------------- causal flash attention, S^T formulation ----------------
// ROUND-12: q-tile 64 -> 128 rows (8 waves, 512 threads); pair (p, 7-p),
//   grid 256 blocks. Each staged kv-tile now serves 8 waves instead of 4:
//   per 128 q-rows the kv sweep is 18 staged iters vs 34 before -> K/V HBM
//   traffic, barriers, and softmax-chain count ~halve. T14 reg-staging kept
//   (kreg/vreg shrink [4]->[2], -16 VGPR). Causal mask per-element only for
//   kt >= 2*qt (last two tiles); low-half lanes run one fully-masked iter
//   (exp -> 0, numerically identical).
__global__ __launch_bounds__(512) void k_attn(const f16* __restrict__ qr,
                                              const f16* __restrict__ kr,
                                              const f16* __restrict__ vt,
                                              const float* __restrict__ pb,
                                              f16* __restrict__ y) {
    __shared__ __align__(16) f16 Ks[2][64 * 136];   // [kv][hd], pad 128->136
    __shared__ __align__(16) f16 Vs[2][128 * 72];   // [hd][kv], pad 64->72
    __shared__ float pbs[2][64];
    int p = blockIdx.x & 3;                          // pair index 0..3
    int bh = blockIdx.x >> 2;
    int b = bh >> 4, h = bh & 15;
    int tid = threadIdx.x;
    int w = tid >> 6, lane = tid & 63, quad = lane >> 4, l16 = lane & 15;
    // per-thread staging indices (512 threads: 2 sub-iters each)
    const int krow0 = tid >> 4, kcol0 = (tid & 15) << 3;     // + i*32 rows
    const int vrow0 = tid >> 3, vcol0 = (tid & 7) << 3;      // + i*64 rows
#pragma unroll
    for (int pass = 0; pass < 2; pass++) {
        int qt = pass ? (7 - p) : p;                 // 128-row q-tile index 0..7
        int q0 = qt << 7;
        int qg = q0 + w * 16 + l16;                  // this lane's q column
        int ktmax = 2 * qt + 1;                      // kv-tiles 0..ktmax
        const f16* Qp = qr + ((size_t)bh * TT + qg) * HDIM;
        half8 qf[4];                                  // B-op: Q[q=l16][hd=kc*32+quad*8+e]
#pragma unroll
        for (int kc = 0; kc < 4; kc++) qf[kc] = *(const half8*)&Qp[kc * 32 + (quad << 3)];
        floatx4 O[8];                                 // O^T[hd][q] C-frags
#pragma unroll
        for (int i = 0; i < 8; i++) O[i] = (floatx4){0.f, 0.f, 0.f, 0.f};
        float mx = -1e30f, ls = 0.f;
        // ---- prologue: stage kv-tile 0 into buffer 0 (direct load->LDS)
        {
            const f16* Kb = kr + (size_t)bh * TT * HDIM;
            const f16* Vb = vt + (size_t)bh * HDIM * TT;
#pragma unroll
            for (int i = 0; i < 2; i++) {
                *(uint4*)&Ks[0][(krow0 + i * 32) * 136 + kcol0] =
                    *(const uint4*)&Kb[(size_t)(krow0 + i * 32) * HDIM + kcol0];
                *(uint4*)&Vs[0][(vrow0 + i * 64) * 72 + vcol0] =
                    *(const uint4*)&Vb[(size_t)(vrow0 + i * 64) * TT + vcol0];
            }
            if (tid < 64) pbs[0][tid] = pb[b * TT + tid];
        }
        __syncthreads();
        int cur = 0;
        for (int kt = 0; kt <= ktmax; kt++) {
            // ---- early-issue kt+1 loads into registers (latency hides under compute)
            uint4 kreg[2], vreg[2];
            float pbnext = 0.f;
            const bool have = (kt < ktmax);
            if (have) {
                const f16* Kb = kr + ((size_t)bh * TT + ((kt + 1) << 6)) * HDIM;
                const f16* Vb = vt + (size_t)bh * HDIM * TT + ((kt + 1) << 6);
#pragma unroll
                for (int i = 0; i < 2; i++) {
                    kreg[i] = *(const uint4*)&Kb[(size_t)(krow0 + i * 32) * HDIM + kcol0];
                    vreg[i] = *(const uint4*)&Vb[(size_t)(vrow0 + i * 64) * TT + vcol0];
                }
                if (tid < 64) pbnext = pb[b * TT + ((kt + 1) << 6) + tid];
            }
            const f16* Kl = Ks[cur];
            const f16* Vl = Vs[cur];
            floatx4 Sv[4];
#pragma unroll
            for (int mc = 0; mc < 4; mc++) Sv[mc] = (floatx4){0.f, 0.f, 0.f, 0.f};
#pragma unroll
            for (int kc = 0; kc < 4; kc++)
#pragma unroll
                for (int mc = 0; mc < 4; mc++) {
                    half8 kf = *(const half8*)&Kl[(mc * 16 + l16) * 136 + kc * 32 + (quad << 3)];
                    Sv[mc] = __builtin_amdgcn_mfma_f32_16x16x32_f16(kf, qf[kc], Sv[mc], 0, 0, 0);
                }
            float pv[4][4];
            float mnew = mx;
            if (kt >= 2 * qt) {          // only the last two tiles can cross the diagonal
#pragma unroll
                for (int mc = 0; mc < 4; mc++) {
                    float4 pbv = *(const float4*)&pbs[cur][mc * 16 + (quad << 2)];
#pragma unroll
                    for (int i = 0; i < 4; i++) {
                        int kv = (kt << 6) + mc * 16 + (quad << 2) + i;
                        float s = (kv <= qg) ? Sv[mc][i] + ((const float*)&pbv)[i] : -1e30f;
                        pv[mc][i] = s;
                        mnew = fmaxf(mnew, s);
                    }
                }
            } else {
#pragma unroll
                for (int mc = 0; mc < 4; mc++) {
                    float4 pbv = *(const float4*)&pbs[cur][mc * 16 + (quad << 2)];
#pragma unroll
                    for (int i = 0; i < 4; i++) {
                        float s = Sv[mc][i] + ((const float*)&pbv)[i];
                        pv[mc][i] = s;
                        mnew = fmaxf(mnew, s);
                    }
                }
            }
            mnew = fmaxf(mnew, __shfl_xor(mnew, 16));
            mnew = fmaxf(mnew, __shfl_xor(mnew, 32));
            float al = __expf(mx - mnew);
            mx = mnew;
            float psum = 0.f;
#pragma unroll
            for (int mc = 0; mc < 4; mc++)
#pragma unroll
                for (int i = 0; i < 4; i++) {
                    float e = __expf(pv[mc][i] - mnew);
                    pv[mc][i] = e;
                    psum += e;
                }
            psum += __shfl_xor(psum, 16);
            psum += __shfl_xor(psum, 32);
            ls = ls * al + psum;
#pragma unroll
            for (int hm = 0; hm < 8; hm++)
#pragma unroll
                for (int i = 0; i < 4; i++) O[hm][i] *= al;
            half4 pf[4];
#pragma unroll
            for (int mc = 0; mc < 4; mc++) {
                pf[mc][0] = (f16)pv[mc][0]; pf[mc][1] = (f16)pv[mc][1];
                pf[mc][2] = (f16)pv[mc][2]; pf[mc][3] = (f16)pv[mc][3];
            }
#pragma unroll
            for (int mc = 0; mc < 4; mc++)
#pragma unroll
                for (int hm = 0; hm < 8; hm++) {
                    half4 vf = *(const half4*)&Vl[(hm * 16 + l16) * 72 + mc * 16 + (quad << 2)];
                    O[hm] = __builtin_amdgcn_mfma_f32_16x16x16f16(vf, pf[mc], O[hm], 0, 0, 0);
                }
            if (have) {
                int nxt = cur ^ 1;
#pragma unroll
                for (int i = 0; i < 2; i++) {
                    *(uint4*)&Ks[nxt][(krow0 + i * 32) * 136 + kcol0] = kreg[i];
                    *(uint4*)&Vs[nxt][(vrow0 + i * 64) * 72 + vcol0] = vreg[i];
                }
                if (tid < 64) pbs[nxt][tid] = pbnext;
            }
            __syncthreads();
            cur ^= 1;
        }
        float inv = 1.0f / ls;
#pragma unroll
        for (int hm = 0; hm < 8; hm++) {
            half4 ov;
#pragma unroll
            for (int i = 0; i < 4; i++) ov[i] = (f16)(O[hm][i] * inv);
            *(half4*)&y[((size_t)b * TT + qg) * CCH + h * HDIM + hm * 16 + (quad << 2)] = ov;
        }
        __syncthreads();   // protect LDS before next pass restages
    }
}

extern "C" void kernel_launch(void* const* d_in, const int* in_sizes, int n_in,
                              void* d_out, int out_size, void* d_ws, size_t ws_size,
                              hipStream_t stream) {
    const float* x   = (const float*)d_in[0];
    const float* cs  = (const float*)d_in[1];
    const int*   tok = (const int*)d_in[2];
    const int*   pm  = (const int*)d_in[3];
    const float* Wa  = (const float*)d_in[4];
    const float* Wp  = (const float*)d_in[5];
    float* out = (float*)d_out;
    char* ws = (char*)d_ws;

    f16* x16 = (f16*)(ws + 0);             // 16 MB ; reused as y after GEMM1
    f16* WaT = (f16*)(ws + 16777216);      // 24 MB
    f16* vt  = (f16*)(ws + 41943040);      // 16 MB   [bh][hd][t] (written by GEMM1)
    f16* WpT = (f16*)(ws + 58720256);      //  8 MB
    float2* tab = (float2*)(ws + 67108864);// 2 MB rope table (gap before qr)
    f16* qr  = (f16*)(ws + 92274688);      // 16 MB
    f16* kr  = (f16*)(ws + 109051904);     // 16 MB
    int*   cnt  = (int*)(ws + 142606336);  // 4 KB
    float* tpos = (float*)(ws + 142610432);// 16 KB
    float* pb   = (float*)(ws + 142626816);// 16 KB
    f16* y   = x16;

    hipMemsetAsync(cnt, 0, NBLK * sizeof(int), stream);
    k_hist<<<MM / 256, 256, 0, stream>>>(tok, cnt);
    k_scan<<<BB, TT, 0, stream>>>(tok, cnt, pm, tpos, pb);
    k_rope<<<MM * 64 / 256, 256, 0, stream>>>(tpos, tab);
    k_prep<<<dim3(192, 32, 3), dim3(32, 8), 0, stream>>>(Wa, Wp, x, WaT, WpT, x16);
    k_gemm8<1><<<768, 512, 0, stream>>>(x16, WaT, nullptr, tab, cs, qr, kr, vt);
    k_attn<<<BB * HH * 4, 512, 0, stream>>>(qr, kr, vt, pb, y);
    k_gemm8<0><<<256, 512, 0, stream>>>(y, WpT, out, nullptr, nullptr, nullptr, nullptr, nullptr);
}